// Round 18
// baseline (624.815 us; speedup 1.0000x reference)
//
#include <hip/hip_runtime.h>
#include <hip/hip_bf16.h>
#include <math.h>

#define B_ 4
#define R_ 1024
#define G_ 8
#define E_ 192
#define H_ 6
#define D_ 32
#define L_ 4
#define F_ 384
#define M_ (B_*R_*G_)              // 32768 rows
static const size_t NBUF = (size_t)M_ * E_;       // 6291456 elems
static const size_t WPL  = 8 * (size_t)E_ * E_ + 2 * (size_t)E_ * F_;  // bf16/layer

typedef __attribute__((ext_vector_type(8))) short bf16x8;
typedef __attribute__((ext_vector_type(8))) unsigned short u16x8;
typedef __attribute__((ext_vector_type(4))) float f32x4;

__device__ __forceinline__ float gelu_exact(float x) {
    return 0.5f * x * (1.0f + erff(x * 0.7071067811865475f));
}
__device__ __forceinline__ unsigned short f2bf(float f) {
    __hip_bfloat16 h = __float2bfloat16(f);
    return *(unsigned short*)&h;
}
__device__ __forceinline__ float bf2f(unsigned short h) {
    union { unsigned u; float f; } v; v.u = ((unsigned)h) << 16; return v.f;
}
__device__ __forceinline__ bf16x8 mk8(unsigned long long lo, unsigned long long hi) {
    union { unsigned long long q[2]; bf16x8 v; } u;
    u.q[0] = lo; u.q[1] = hi; return u.v;
}

// ---- one-shot: transpose+convert all weights to Wt[N][K] bf16.
// Scale folds: Wq1 *= 1/sqrt(D); Wq2 *= log2(e)/sqrt(D)  (attn2 runs in exp2 domain).
__global__ __launch_bounds__(256)
void k_convw_all(const float* __restrict__ Wq1, const float* __restrict__ Wk1,
                 const float* __restrict__ Wv1, const float* __restrict__ Wo1,
                 const float* __restrict__ Wq2, const float* __restrict__ Wk2,
                 const float* __restrict__ Wv2, const float* __restrict__ Wo2,
                 const float* __restrict__ W1,  const float* __restrict__ W2,
                 unsigned short* __restrict__ Wt)
{
    const int t = blockIdx.x;
    const int layer = t / 432;
    const int r = t % 432;
    const float* src; unsigned short* dst; int K, N; float scale = 1.f; int tile;
    if (r < 288) {
        const int w = r / 36; tile = r % 36; K = E_; N = E_;
        const float* tab[8] = {Wq1, Wk1, Wv1, Wo1, Wq2, Wk2, Wv2, Wo2};
        src = tab[w] + (size_t)layer * E_ * E_;
        dst = Wt + (size_t)layer * WPL + (size_t)w * E_ * E_;
        if (w == 0) scale = 0.17677669529663687f;                       // 1/sqrt(32)
        if (w == 4) scale = 0.17677669529663687f * 1.4426950408889634f; // log2e/sqrt(32)
    } else if (r < 360) {
        tile = r - 288; K = E_; N = F_;
        src = W1 + (size_t)layer * E_ * F_;
        dst = Wt + (size_t)layer * WPL + 8 * (size_t)E_ * E_;
    } else {
        tile = r - 360; K = F_; N = E_;
        src = W2 + (size_t)layer * E_ * F_;
        dst = Wt + (size_t)layer * WPL + 8 * (size_t)E_ * E_ + (size_t)E_ * F_;
    }
    const int ntx = N / 32;
    const int kb = (tile / ntx) * 32, nb = (tile % ntx) * 32;
    __shared__ float tl[32][33];
    const int tx = threadIdx.x & 31, ty = threadIdx.x >> 5;
    for (int i2 = 0; i2 < 32; i2 += 8)
        tl[ty + i2][tx] = src[(size_t)(kb + ty + i2) * N + nb + tx];
    __syncthreads();
    for (int i2 = 0; i2 < 32; i2 += 8)
        dst[(size_t)(nb + ty + i2) * K + kb + tx] = f2bf(tl[tx][ty + i2] * scale);
}

// ---- MFMA GEMM, tile 64 x 192, BK=32, 4 waves, reg-prefetch pipeline (R8 form).
// EPI: 0 = store bf16 at [m][n0+n], ldc; 1 = gelu -> bf16, ldc.
template<bool ABF16, int EPI>
__global__ __launch_bounds__(256)
void k_gemm_mfma(const void* __restrict__ Ap, const unsigned short* __restrict__ Wt,
                 void* __restrict__ Cp, int ldc, int K)
{
    __shared__ unsigned short As[64][40];
    __shared__ unsigned short Bs[192][40];
    const int m0 = blockIdx.x * 64;
    const int n0 = blockIdx.y * 192;
    const int tid = threadIdx.x;
    const int w = tid >> 6, lane = tid & 63, l15 = lane & 15, g = lane >> 4;
    const int arow = tid >> 2, akoff = (tid & 3) << 3;
    f32x4 acc[4][3];
#pragma unroll
    for (int mt = 0; mt < 4; ++mt)
#pragma unroll
        for (int nt = 0; nt < 3; ++nt)
#pragma unroll
            for (int r2 = 0; r2 < 4; ++r2) acc[mt][nt][r2] = 0.f;
    const int nK = K >> 5;

    float4 ax, ay; u16x8 av; u16x8 bv0, bv1, bv2;
    auto gload = [&](int k0) {
        if (ABF16) {
            av = *(const u16x8*)((const unsigned short*)Ap + (size_t)(m0 + arow) * K + k0 + akoff);
        } else {
            const float* ap = (const float*)Ap + (size_t)(m0 + arow) * K + k0 + akoff;
            ax = *(const float4*)ap; ay = *(const float4*)(ap + 4);
        }
        bv0 = *(const u16x8*)(Wt + (size_t)(n0 + arow      ) * K + k0 + akoff);
        bv1 = *(const u16x8*)(Wt + (size_t)(n0 + arow +  64) * K + k0 + akoff);
        bv2 = *(const u16x8*)(Wt + (size_t)(n0 + arow + 128) * K + k0 + akoff);
    };
    auto swrite = [&]() {
        u16x8 aw;
        if (ABF16) aw = av;
        else {
            aw[0] = f2bf(ax.x); aw[1] = f2bf(ax.y); aw[2] = f2bf(ax.z); aw[3] = f2bf(ax.w);
            aw[4] = f2bf(ay.x); aw[5] = f2bf(ay.y); aw[6] = f2bf(ay.z); aw[7] = f2bf(ay.w);
        }
        *(u16x8*)&As[arow][akoff] = aw;
        *(u16x8*)&Bs[arow][akoff] = bv0;
        *(u16x8*)&Bs[arow + 64][akoff] = bv1;
        *(u16x8*)&Bs[arow + 128][akoff] = bv2;
    };

    gload(0);
    for (int kc = 0; kc < nK; ++kc) {
        __syncthreads();
        swrite();
        __syncthreads();
        if (kc + 1 < nK) gload((kc + 1) << 5);
        bf16x8 af[4], bfr[3];
#pragma unroll
        for (int mt = 0; mt < 4; ++mt) af[mt] = *(const bf16x8*)&As[mt * 16 + l15][g * 8];
#pragma unroll
        for (int nt = 0; nt < 3; ++nt) bfr[nt] = *(const bf16x8*)&Bs[w * 48 + nt * 16 + l15][g * 8];
#pragma unroll
        for (int mt = 0; mt < 4; ++mt)
#pragma unroll
            for (int nt = 0; nt < 3; ++nt)
                acc[mt][nt] = __builtin_amdgcn_mfma_f32_16x16x32_bf16(af[mt], bfr[nt], acc[mt][nt], 0, 0, 0);
    }

#pragma unroll
    for (int mt = 0; mt < 4; ++mt)
#pragma unroll
        for (int r2 = 0; r2 < 4; ++r2) {
            const int m = m0 + mt * 16 + g * 4 + r2;
#pragma unroll
            for (int nt = 0; nt < 3; ++nt) {
                const int n = w * 48 + nt * 16 + l15;
                float v = acc[mt][nt][r2];
                if (EPI == 1) v = gelu_exact(v);
                ((unsigned short*)Cp)[(size_t)m * ldc + n0 + n] = f2bf(v);
            }
        }
}

// ---- MFMA GEMM + residual + row-RMSNorm, tile 32 x 192, 4 waves, grid M/32.
// EPI: 2 = ->bf16, transpose X->XR; 3 = ->bf16, XR->X; 4 = ->f32; 5 = ->bf16.
template<bool RESBF16, int EPI>
__global__ __launch_bounds__(256)
void k_gemm_rms32(const unsigned short* __restrict__ Ap, const unsigned short* __restrict__ Wt,
                  const void* __restrict__ Resp, const float* __restrict__ gvec,
                  void* __restrict__ Cp, int K)
{
    __shared__ unsigned short As[32][40];
    __shared__ unsigned short Bs[192][40];
    __shared__ float ss_red[4][16];
    const int m0 = blockIdx.x * 32;
    const int tid = threadIdx.x;
    const int w = tid >> 6, lane = tid & 63, l15 = lane & 15, g = lane >> 4;
    const int mt = w & 1, nh = w >> 1;
    const int arow = tid >> 2, akoff = (tid & 3) << 3;
    f32x4 acc[6];
#pragma unroll
    for (int nt = 0; nt < 6; ++nt)
#pragma unroll
        for (int r2 = 0; r2 < 4; ++r2) acc[nt][r2] = 0.f;
    const int nK = K >> 5;

    u16x8 av, bv0, bv1, bv2;
    auto gload = [&](int k0) {
        if (tid < 128)
            av = *(const u16x8*)(Ap + (size_t)(m0 + arow) * K + k0 + akoff);
        bv0 = *(const u16x8*)(Wt + (size_t)(arow      ) * K + k0 + akoff);
        bv1 = *(const u16x8*)(Wt + (size_t)(arow +  64) * K + k0 + akoff);
        bv2 = *(const u16x8*)(Wt + (size_t)(arow + 128) * K + k0 + akoff);
    };
    auto swrite = [&]() {
        if (tid < 128) *(u16x8*)&As[arow][akoff] = av;
        *(u16x8*)&Bs[arow][akoff] = bv0;
        *(u16x8*)&Bs[arow + 64][akoff] = bv1;
        *(u16x8*)&Bs[arow + 128][akoff] = bv2;
    };

    gload(0);
    for (int kc = 0; kc < nK; ++kc) {
        __syncthreads();
        swrite();
        __syncthreads();
        if (kc + 1 < nK) gload((kc + 1) << 5);
        bf16x8 af = *(const bf16x8*)&As[mt * 16 + l15][g * 8];
        bf16x8 bfr[6];
#pragma unroll
        for (int nt = 0; nt < 6; ++nt) bfr[nt] = *(const bf16x8*)&Bs[nh * 96 + nt * 16 + l15][g * 8];
#pragma unroll
        for (int nt = 0; nt < 6; ++nt)
            acc[nt] = __builtin_amdgcn_mfma_f32_16x16x32_bf16(af, bfr[nt], acc[nt], 0, 0, 0);
    }

    float ssp[4] = {0.f, 0.f, 0.f, 0.f};
#pragma unroll
    for (int r2 = 0; r2 < 4; ++r2) {
        const int m = m0 + mt * 16 + g * 4 + r2;
#pragma unroll
        for (int nt = 0; nt < 6; ++nt) {
            const int n = nh * 96 + nt * 16 + l15;
            float rres = RESBF16 ? bf2f(((const unsigned short*)Resp)[(size_t)m * E_ + n])
                                 : ((const float*)Resp)[(size_t)m * E_ + n];
            float v = acc[nt][r2] + rres;
            acc[nt][r2] = v;
            ssp[r2] += v * v;
        }
    }
#pragma unroll
    for (int off = 1; off < 16; off <<= 1)
#pragma unroll
        for (int r2 = 0; r2 < 4; ++r2)
            ssp[r2] += __shfl_xor(ssp[r2], off);
    if (l15 == 0) {
#pragma unroll
        for (int r2 = 0; r2 < 4; ++r2)
            ss_red[w][g * 4 + r2] = ssp[r2];
    }
    __syncthreads();
#pragma unroll
    for (int r2 = 0; r2 < 4; ++r2) {
        const int lr = g * 4 + r2;
        const float ss = ss_red[mt][lr] + ss_red[2 + mt][lr];
        const float inv = rsqrtf(ss * (1.0f / 192.0f) + 1.1920929e-07f);
        const int m = m0 + mt * 16 + lr;
        size_t orow;
        if (EPI == 2) {        // X -> XR
            const int b = m >> 13, rr = (m >> 3) & 1023, gg = m & 7;
            orow = (((size_t)b * G_ + gg) << 10) + rr;
        } else if (EPI == 3) { // XR -> X
            const int b = m >> 13, gg = (m >> 10) & 7, rr = m & 1023;
            orow = ((((size_t)b << 10) + rr) << 3) + gg;
        } else {
            orow = m;
        }
#pragma unroll
        for (int nt = 0; nt < 6; ++nt) {
            const int n = nh * 96 + nt * 16 + l15;
            const float v = acc[nt][r2] * inv * gvec[n];
            if (EPI == 4) ((float*)Cp)[orow * E_ + n] = v;
            else          ((unsigned short*)Cp)[orow * E_ + n] = f2bf(v);
        }
    }
}

// ---- Fused feature-attention block v6: v5 + phase 4 = QKV2 GEMM fused in.
// Yn rows are complete in-block, so QKV2 = Yn @ Wqkv2^T runs here, deleting
// the separate QKV2 dispatch (and its Ynb re-read). 7 barriers.
template<bool AF32>
__global__ __launch_bounds__(256)
void k_featblock(const void* __restrict__ Xin, const unsigned short* __restrict__ Wqkv,
                 const unsigned short* __restrict__ Wo, const unsigned short* __restrict__ Wqkv2,
                 const float* __restrict__ gvec, unsigned short* __restrict__ Ynb,
                 unsigned short* __restrict__ QKVout)
{
    __shared__ __align__(16) unsigned short raw[18688];      // 37376 B
    __shared__ __align__(16) unsigned short AsTl[32][200];   // A -> Tl -> Yn

    unsigned short (*QKVl)[584] = (unsigned short (*)[584])raw;
    const int m0 = blockIdx.x * 32;
    const int tid = threadIdx.x;
    const int w = tid >> 6, lane = tid & 63, l15 = lane & 15, g = lane >> 4;

    // ---- stage A once (32 x 192, coalesced) ----
#pragma unroll
    for (int j = 0; j < 3; ++j) {
        const int v = tid + 256 * j;
        const int row = v / 24, ch = v % 24;
        u16x8 aw;
        if (AF32) {
            const float* ap = (const float*)Xin + (size_t)(m0 + row) * E_ + ch * 8;
            float4 x = *(const float4*)ap, y = *(const float4*)(ap + 4);
            aw[0] = f2bf(x.x); aw[1] = f2bf(x.y); aw[2] = f2bf(x.z); aw[3] = f2bf(x.w);
            aw[4] = f2bf(y.x); aw[5] = f2bf(y.y); aw[6] = f2bf(y.z); aw[7] = f2bf(y.w);
        } else {
            aw = *(const u16x8*)((const unsigned short*)Xin + (size_t)(m0 + row) * E_ + ch * 8);
        }
        *(u16x8*)&AsTl[row][ch * 8] = aw;
    }
    __syncthreads();   // B1

    // ---- phase 1: QKV1 = A @ Wqkv^T, per-wave swizzled B slices ----
    f32x4 acc[2][9];
#pragma unroll
    for (int mt = 0; mt < 2; ++mt)
#pragma unroll
        for (int nt = 0; nt < 9; ++nt)
#pragma unroll
            for (int r2 = 0; r2 < 4; ++r2) acc[mt][nt][r2] = 0.f;

    unsigned short* slice1 = raw + w * 4608;          // [144][32] swizzled
    u16x8 bv[9];
    auto gload9 = [&](const unsigned short* W, int k0) {
#pragma unroll
        for (int j = 0; j < 9; ++j) {
            const int v = lane + 64 * j;
            bv[j] = *(const u16x8*)(W + (size_t)(w * 144 + (v >> 2)) * E_ + k0 + ((v & 3) << 3));
        }
    };
    auto swrite9 = [&]() {
#pragma unroll
        for (int j = 0; j < 9; ++j) {
            const int v = lane + 64 * j;
            const int row = v >> 2;
            const int pos = (v & 3) ^ (row & 3);
            *(u16x8*)&slice1[row * 32 + pos * 8] = bv[j];
        }
    };
    const int rb1 = g ^ (l15 & 3);

    gload9(Wqkv, 0);
    swrite9();
    gload9(Wqkv, 32);
#pragma unroll
    for (int kc = 0; kc < 6; ++kc) {
        const int k0 = kc << 5;
        bf16x8 af0 = *(const bf16x8*)&AsTl[l15][k0 + g * 8];
        bf16x8 af1 = *(const bf16x8*)&AsTl[16 + l15][k0 + g * 8];
        bf16x8 bfr[9];
#pragma unroll
        for (int nt = 0; nt < 9; ++nt)
            bfr[nt] = *(const bf16x8*)&slice1[(nt * 16 + l15) * 32 + rb1 * 8];
#pragma unroll
        for (int nt = 0; nt < 9; ++nt) {
            acc[0][nt] = __builtin_amdgcn_mfma_f32_16x16x32_bf16(af0, bfr[nt], acc[0][nt], 0, 0, 0);
            acc[1][nt] = __builtin_amdgcn_mfma_f32_16x16x32_bf16(af1, bfr[nt], acc[1][nt], 0, 0, 0);
        }
        if (kc + 1 < 6) swrite9();
        if (kc + 2 < 6) gload9(Wqkv, (kc + 2) << 5);
    }
    __syncthreads();   // B2

    // spill QKV1 to QKVl
#pragma unroll
    for (int mt = 0; mt < 2; ++mt)
#pragma unroll
        for (int r2 = 0; r2 < 4; ++r2)
#pragma unroll
            for (int nt = 0; nt < 9; ++nt)
                QKVl[mt * 16 + g * 4 + r2][w * 144 + nt * 16 + l15] = f2bf(acc[mt][nt][r2]);

    // prefetch phase-3 chunk-0 weights
    u16x8 bo[3];
    auto gload3 = [&](int k0) {
#pragma unroll
        for (int j = 0; j < 3; ++j) {
            const int v = lane + 64 * j;
            bo[j] = *(const u16x8*)(Wo + (size_t)(w * 48 + (v >> 2)) * E_ + k0 + ((v & 3) << 3));
        }
    };
    gload3(0);
    __syncthreads();   // B3

    // ---- phase 2: attn1 ----
    {
        const int i = lane >> 3, j = lane & 7;
        const int r0 = w * 8;
#pragma unroll
        for (int h = 0; h < 6; ++h) {
            float s = 0.f;
#pragma unroll
            for (int d8 = 0; d8 < 4; ++d8) {
                u16x8 qv = *(const u16x8*)&QKVl[r0 + i][h * 32 + d8 * 8];
                u16x8 kv = *(const u16x8*)&QKVl[r0 + j][192 + h * 32 + d8 * 8];
#pragma unroll
                for (int e = 0; e < 8; ++e) s += bf2f(qv[e]) * bf2f(kv[e]);
            }
            float mx = s;
#pragma unroll
            for (int off = 1; off < 8; off <<= 1) mx = fmaxf(mx, __shfl_xor(mx, off));
            float p = __expf(s - mx);
            float sum = p;
#pragma unroll
            for (int off = 1; off < 8; off <<= 1) sum += __shfl_xor(sum, off);
            p /= sum;
            const int base = lane & ~7;
            float o0 = 0.f, o1 = 0.f, o2 = 0.f, o3 = 0.f;
#pragma unroll
            for (int jj = 0; jj < 8; ++jj) {
                float pj = __shfl(p, base + jj);
                ushort4 vv = *(const ushort4*)&QKVl[r0 + jj][384 + h * 32 + j * 4];
                o0 += pj * bf2f(vv.x); o1 += pj * bf2f(vv.y);
                o2 += pj * bf2f(vv.z); o3 += pj * bf2f(vv.w);
            }
            ushort4 ov; ov.x = f2bf(o0); ov.y = f2bf(o1); ov.z = f2bf(o2); ov.w = f2bf(o3);
            *(ushort4*)&AsTl[r0 + i][h * 32 + j * 4] = ov;   // Tl overlays A
        }
    }

    // preload epilogue residual
    float rv[2][4][3];
#pragma unroll
    for (int mt = 0; mt < 2; ++mt)
#pragma unroll
        for (int r2 = 0; r2 < 4; ++r2) {
            const int m = m0 + mt * 16 + g * 4 + r2;
#pragma unroll
            for (int nt = 0; nt < 3; ++nt) {
                const int n = w * 48 + nt * 16 + l15;
                rv[mt][r2][nt] = AF32 ? ((const float*)Xin)[(size_t)m * E_ + n]
                                      : bf2f(((const unsigned short*)Xin)[(size_t)m * E_ + n]);
            }
        }
    __syncthreads();   // B4

    // ---- phase 3: T @ wo1^T, per-wave swizzled Bo slices ----
    unsigned short* slice3 = raw + w * 1536;          // [48][32] swizzled
    f32x4 acc2[2][3];
#pragma unroll
    for (int mt = 0; mt < 2; ++mt)
#pragma unroll
        for (int nt = 0; nt < 3; ++nt)
#pragma unroll
            for (int r2 = 0; r2 < 4; ++r2) acc2[mt][nt][r2] = 0.f;

    auto swrite3 = [&]() {
#pragma unroll
        for (int j = 0; j < 3; ++j) {
            const int v = lane + 64 * j;
            const int row = v >> 2;
            const int pos = (v & 3) ^ (row & 3);
            *(u16x8*)&slice3[row * 32 + pos * 8] = bo[j];
        }
    };
    swrite3();
    gload3(32);
#pragma unroll
    for (int kc = 0; kc < 6; ++kc) {
        const int k0 = kc << 5;
        bf16x8 af0 = *(const bf16x8*)&AsTl[l15][k0 + g * 8];
        bf16x8 af1 = *(const bf16x8*)&AsTl[16 + l15][k0 + g * 8];
        bf16x8 bfr[3];
#pragma unroll
        for (int nt = 0; nt < 3; ++nt)
            bfr[nt] = *(const bf16x8*)&slice3[(nt * 16 + l15) * 32 + rb1 * 8];
#pragma unroll
        for (int nt = 0; nt < 3; ++nt) {
            acc2[0][nt] = __builtin_amdgcn_mfma_f32_16x16x32_bf16(af0, bfr[nt], acc2[0][nt], 0, 0, 0);
            acc2[1][nt] = __builtin_amdgcn_mfma_f32_16x16x32_bf16(af1, bfr[nt], acc2[1][nt], 0, 0, 0);
        }
        if (kc + 1 < 6) swrite3();
        if (kc + 2 < 6) gload3((kc + 2) << 5);
    }
    __syncthreads();   // B5: Tl reads + slice3 reads done

    // prefetch phase-4 chunk-0 weights (hide under epilogue)
    gload9(Wqkv2, 0);

    // ---- epilogue: +res, row-RMS*g1, write Ynb (XR) + Yn -> AsTl ----
    float* S = (float*)(raw + 6400);
    float ssp[2][4] = {};
#pragma unroll
    for (int mt = 0; mt < 2; ++mt)
#pragma unroll
        for (int r2 = 0; r2 < 4; ++r2) {
#pragma unroll
            for (int nt = 0; nt < 3; ++nt) {
                float v = acc2[mt][nt][r2] + rv[mt][r2][nt];
                acc2[mt][nt][r2] = v;
                ssp[mt][r2] += v * v;
            }
        }
#pragma unroll
    for (int off = 1; off < 16; off <<= 1)
#pragma unroll
        for (int mt = 0; mt < 2; ++mt)
#pragma unroll
            for (int r2 = 0; r2 < 4; ++r2)
                ssp[mt][r2] += __shfl_xor(ssp[mt][r2], off);
    if (l15 == 0) {
#pragma unroll
        for (int mt = 0; mt < 2; ++mt)
#pragma unroll
            for (int r2 = 0; r2 < 4; ++r2)
                S[w * 32 + mt * 16 + g * 4 + r2] = ssp[mt][r2];
    }
    __syncthreads();   // B6
    int orows[2][4];
#pragma unroll
    for (int mt = 0; mt < 2; ++mt)
#pragma unroll
        for (int r2 = 0; r2 < 4; ++r2) {
            const int row = mt * 16 + g * 4 + r2;
            const float ss = S[row] + S[32 + row] + S[64 + row] + S[96 + row];
            const float inv = rsqrtf(ss * (1.0f / 192.0f) + 1.1920929e-07f);
            const int m = m0 + row;
            const int b = m >> 13, rr = (m >> 3) & 1023, gg = m & 7;
            const size_t orow = (((size_t)(b * G_ + gg)) << 10) + rr;
            orows[mt][r2] = (int)orow;
#pragma unroll
            for (int nt = 0; nt < 3; ++nt) {
                const int n = w * 48 + nt * 16 + l15;
                const unsigned short yb = f2bf(acc2[mt][nt][r2] * inv * gvec[n]);
                Ynb[orow * E_ + n] = yb;
                AsTl[row][n] = yb;                     // Yn overlays Tl
            }
        }
    __syncthreads();   // B7: S reads + AsTl Yn writes done before phase-4

    // ---- phase 4: QKV2 = Yn @ Wqkv2^T, same machinery as phase 1 ----
    f32x4 acc4[2][9];
#pragma unroll
    for (int mt = 0; mt < 2; ++mt)
#pragma unroll
        for (int nt = 0; nt < 9; ++nt)
#pragma unroll
            for (int r2 = 0; r2 < 4; ++r2) acc4[mt][nt][r2] = 0.f;

    swrite9();
    gload9(Wqkv2, 32);
#pragma unroll
    for (int kc = 0; kc < 6; ++kc) {
        const int k0 = kc << 5;
        bf16x8 af0 = *(const bf16x8*)&AsTl[l15][k0 + g * 8];
        bf16x8 af1 = *(const bf16x8*)&AsTl[16 + l15][k0 + g * 8];
        bf16x8 bfr[9];
#pragma unroll
        for (int nt = 0; nt < 9; ++nt)
            bfr[nt] = *(const bf16x8*)&slice1[(nt * 16 + l15) * 32 + rb1 * 8];
#pragma unroll
        for (int nt = 0; nt < 9; ++nt) {
            acc4[0][nt] = __builtin_amdgcn_mfma_f32_16x16x32_bf16(af0, bfr[nt], acc4[0][nt], 0, 0, 0);
            acc4[1][nt] = __builtin_amdgcn_mfma_f32_16x16x32_bf16(af1, bfr[nt], acc4[1][nt], 0, 0, 0);
        }
        if (kc + 1 < 6) swrite9();
        if (kc + 2 < 6) gload9(Wqkv2, (kc + 2) << 5);
    }

    // write QKV2 at XR-mapped rows
#pragma unroll
    for (int mt = 0; mt < 2; ++mt)
#pragma unroll
        for (int r2 = 0; r2 < 4; ++r2) {
            const size_t orow = (size_t)orows[mt][r2];
#pragma unroll
            for (int nt = 0; nt < 9; ++nt)
                QKVout[orow * 576 + w * 144 + nt * 16 + l15] = f2bf(acc4[mt][nt][r2]);
        }
}

// ---- Row attention (R14 form, NO max-tracking). ----
__global__ __launch_bounds__(256)
void k_attn2(const unsigned short* __restrict__ QKV, unsigned short* __restrict__ T,
             const int* __restrict__ sep_ptr)
{
    __shared__ __align__(16) unsigned short K_lds[64][40];
    __shared__ __align__(16) unsigned short V_lds[2048];   // [dg(2)][kblk(16)][4][16]

    const int sep = *sep_ptr;
    const int bid = blockIdx.x;
    const int sh = ((bid >> 7) << 3) | (bid & 7);   // same (s,h) => same XCD
    const int qtile = (bid >> 3) & 15;
    const int s = sh / H_, h = sh % H_;
    const int q0 = qtile * 64;

    const int tid = threadIdx.x;
    const int w = tid >> 6;
    const int lane = tid & 63;
    const int l15 = lane & 15;
    const int g = lane >> 4;

    const int qrow = q0 + w * 16 + l15;
    u16x8 qf = *(const u16x8*)(QKV + ((size_t)s * R_ + qrow) * 576 + h * D_ + g * 8);

    u16x8 onesu;
#pragma unroll
    for (int e = 0; e < 8; ++e) onesu[e] = 0x3F80;  // bf16 1.0
    const bf16x8 onesf = (bf16x8)onesu;

    const bool lo = (q0 < sep);
    const bool hi = (q0 + 64 > sep);
    const int npass = (lo && hi) ? 2 : 1;
    const int nChunk = (sep + 63) >> 6;

    const int skey = tid >> 2;
    const int sg   = tid & 3;
    const int vst = ((sg >> 1) * 16 + (skey >> 2)) * 64 + (skey & 3) * 16 + (sg & 1) * 8;
    const unsigned vaddr = (unsigned)(size_t)&V_lds[0] + (unsigned)(g * 128 + l15 * 2);

    for (int pass = 0; pass < npass; ++pass) {
        const int hk = (pass == 0) ? (lo ? h : 0) : 0;
        const unsigned short* Kb = QKV + (size_t)s * R_ * 576 + 192 + hk * D_;
        const unsigned short* Vb = QKV + (size_t)s * R_ * 576 + 384 + hk * D_;

        f32x4 o0 = {0.f, 0.f, 0.f, 0.f};
        f32x4 o1 = {0.f, 0.f, 0.f, 0.f};
        f32x4 o2 = {0.f, 0.f, 0.f, 0.f};   // ones-row: running sum of P

        u16x8 kv_k = *(const u16x8*)(Kb + (size_t)skey * 576 + sg * 8);
        u16x8 kv_v = *(const u16x8*)(Vb + (size_t)skey * 576 + sg * 8);

        for (int kc = 0; kc < nChunk; ++kc) {
            const int kbase = kc * 64;
            const bool full = (kbase + 64 <= sep);
            __syncthreads();
            *(u16x8*)&K_lds[skey][sg * 8] = kv_k;
            *(u16x8*)&V_lds[vst] = kv_v;
            __syncthreads();
            if (kc + 1 < nChunk) {
                kv_k = *(const u16x8*)(Kb + (size_t)(kbase + 64 + skey) * 576 + sg * 8);
                kv_v = *(const u16x8*)(Vb + (size_t)(kbase + 64 + skey) * 576 + sg * 8);
            }

            f32x4 sc[4];
            const f32x4 zf = {0.f, 0.f, 0.f, 0.f};
            __builtin_amdgcn_s_setprio(1);
#pragma unroll
            for (int t = 0; t < 4; ++t) {
                bf16x8 a = *(const bf16x8*)&K_lds[t * 16 + l15][g * 8];
                sc[t] = __builtin_amdgcn_mfma_f32_16x16x32_bf16(a, (bf16x8)qf, zf, 0, 0, 0);
            }
            __builtin_amdgcn_s_setprio(0);
            if (!full) {
#pragma unroll
                for (int t = 0; t < 4; ++t)
#pragma unroll
                    for (int r = 0; r < 4; ++r)
                        if (kbase + t * 16 + g * 4 + r >= sep) sc[t][r] = -1e30f;
            }
            // P = exp2(s) directly (implicit max = 0); pack to B-fragments.
            bf16x8 pb0, pb1;
            {
                u16x8 p0, p1;
#pragma unroll
                for (int r = 0; r < 4; ++r) {
                    p0[r]     = f2bf(exp2f(sc[0][r]));
                    p0[4 + r] = f2bf(exp2f(sc[1][r]));
                    p1[r]     = f2bf(exp2f(sc[2][r]));
                    p1[4 + r] = f2bf(exp2f(sc[3][r]));
                }
                pb0 = (bf16x8)p0; pb1 = (bf16x8)p1;
            }
            unsigned long long t0, t1, t2, t3, t4, t5, t6, t7;
            asm volatile(
                "ds_read_b64_tr_b16 %0, %8 offset:0\n\t"
                "ds_read_b64_tr_b16 %1, %8 offset:512\n\t"
                "ds_read_b64_tr_b16 %2, %8 offset:1024\n\t"
                "ds_read_b64_tr_b16 %3, %8 offset:1536\n\t"
                "ds_read_b64_tr_b16 %4, %8 offset:2048\n\t"
                "ds_read_b64_tr_b16 %5, %8 offset:2560\n\t"
                "ds_read_b64_tr_b16 %6, %8 offset:3072\n\t"
                "ds_read_b64_tr_b16 %7, %8 offset:3584\n\t"
                "s_waitcnt lgkmcnt(0)"
                : "=&v"(t0), "=&v"(t1), "=&v"(t2), "=&v"(t3),
                  "=&v"(t4), "=&v"(t5), "=&v"(t6), "=&v"(t7)
                : "v"(vaddr)
                : "memory");
            __builtin_amdgcn_sched_barrier(0);
            __builtin_amdgcn_s_setprio(1);
            o0 = __builtin_amdgcn_mfma_f32_16x16x32_bf16(mk8(t0, t1), pb0, o0, 0, 0, 0);
            o1 = __builtin_amdgcn_mfma_f32_16x16x32_bf16(mk8(t4, t5), pb0, o1, 0, 0, 0);
            o2 = __builtin_amdgcn_mfma_f32_16x16x32_bf16(onesf,       pb0, o2, 0, 0, 0);
            o0 = __builtin_amdgcn_mfma_f32_16x16x32_bf16(mk8(t2, t3), pb1, o0, 0, 0, 0);
            o1 = __builtin_amdgcn_mfma_f32_16x16x32_bf16(mk8(t6, t7), pb1, o1, 0, 0, 0);
            o2 = __builtin_amdgcn_mfma_f32_16x16x32_bf16(onesf,       pb1, o2, 0, 0, 0);
            __builtin_amdgcn_s_setprio(0);
        }

        const bool valid = (npass == 1) || (pass == 0 ? (qrow < sep) : (qrow >= sep));
        if (valid) {
            const float inv = 1.f / o2[0];
            unsigned short* tp = T + ((size_t)s * R_ + qrow) * E_ + h * D_;
            ushort4 v0, v1;
            v0.x = f2bf(o0[0] * inv); v0.y = f2bf(o0[1] * inv);
            v0.z = f2bf(o0[2] * inv); v0.w = f2bf(o0[3] * inv);
            v1.x = f2bf(o1[0] * inv); v1.y = f2bf(o1[1] * inv);
            v1.z = f2bf(o1[2] * inv); v1.w = f2bf(o1[3] * inv);
            *(ushort4*)(tp + g * 4)      = v0;
            *(ushort4*)(tp + 16 + g * 4) = v1;
        }
    }
}

extern "C" void kernel_launch(void* const* d_in, const int* in_sizes, int n_in,
                              void* d_out, int out_size, void* d_ws, size_t ws_size,
                              hipStream_t stream) {
    const float* hidden = (const float*)d_in[0];
    const float* Wq1 = (const float*)d_in[1];
    const float* Wk1 = (const float*)d_in[2];
    const float* Wv1 = (const float*)d_in[3];
    const float* Wo1 = (const float*)d_in[4];
    const float* Wq2 = (const float*)d_in[5];
    const float* Wk2 = (const float*)d_in[6];
    const float* Wv2 = (const float*)d_in[7];
    const float* Wo2 = (const float*)d_in[8];
    const float* W1  = (const float*)d_in[9];
    const float* W2  = (const float*)d_in[10];
    const float* g1  = (const float*)d_in[11];
    const float* g2  = (const float*)d_in[12];
    const float* g3  = (const float*)d_in[13];
    const int*   sep = (const int*)d_in[14];

    float* Xout = (float*)d_out;                    // final f32 X-layout output
    unsigned short* ws = (unsigned short*)d_ws;
    unsigned short* QKVb = ws;                      // [M][576] bf16 (aliases H1 [M][384])
    unsigned short* Tb   = QKVb + (size_t)M_ * 576;
    unsigned short* Ynb  = Tb + NBUF;               // rms-g1 output, XR layout
    unsigned short* Xcb  = Ynb + NBUF;              // rms-g2 output, X layout
    unsigned short* Xb   = Xcb + NBUF;              // inter-layer residual (layers 0-2)
    unsigned short* Wt   = Xb + NBUF;
    unsigned short* H1b  = QKVb;

    const dim3 blk(256);
    const dim3 gW1(M_ / 64, 2);
    const dim3 g32(M_ / 32);                        // 1024 blocks
    const dim3 gA2(32 * H_ * 16);

    k_convw_all<<<dim3(432 * L_), blk, 0, stream>>>(Wq1, Wk1, Wv1, Wo1, Wq2, Wk2, Wv2, Wo2, W1, W2, Wt);

    for (int i = 0; i < L_; ++i) {
        unsigned short* wl = Wt + (size_t)i * WPL;
        const unsigned short* wqkv1 = wl;
        const unsigned short* wo1   = wl + 3 * (size_t)E_ * E_;
        const unsigned short* wqkv2 = wl + 4 * (size_t)E_ * E_;
        const unsigned short* wo2   = wl + 7 * (size_t)E_ * E_;
        const unsigned short* w1    = wl + 8 * (size_t)E_ * E_;
        const unsigned short* w2    = wl + 8 * (size_t)E_ * E_ + (size_t)E_ * F_;
        const float* g1i = g1 + (size_t)i * E_;
        const float* g2i = g2 + (size_t)i * E_;
        const float* g3i = g3 + (size_t)i * E_;

        // --- fused feature-attention + QKV2 block: X/hidden -> Ynb (XR) + QKVb ---
        if (i == 0)
            k_featblock<true><<<g32, blk, 0, stream>>>(hidden, wqkv1, wo1, wqkv2, g1i, Ynb, QKVb);
        else
            k_featblock<false><<<g32, blk, 0, stream>>>(Xb, wqkv1, wo1, wqkv2, g1i, Ynb, QKVb);
        // --- row attention block ---
        k_attn2<<<gA2, blk, 0, stream>>>(QKVb, Tb, sep);
        k_gemm_rms32<true, 3><<<g32, blk, 0, stream>>>(Tb, wo2, Ynb, g2i, Xcb, E_);
        // --- MLP block ---
        k_gemm_mfma<true, 1><<<gW1, blk, 0, stream>>>(Xcb, w1, H1b, F_, E_);
        if (i == L_ - 1)
            k_gemm_rms32<true, 4><<<g32, blk, 0, stream>>>(H1b, w2, Xcb, g3i, Xout, F_);
        else
            k_gemm_rms32<true, 5><<<g32, blk, 0, stream>>>(H1b, w2, Xcb, g3i, Xb, F_);
    }
}

// Round 19
// 607.653 us; speedup vs baseline: 1.0282x; 1.0282x over previous
//
#include <hip/hip_runtime.h>
#include <hip/hip_bf16.h>
#include <math.h>

#define B_ 4
#define R_ 1024
#define G_ 8
#define E_ 192
#define H_ 6
#define D_ 32
#define L_ 4
#define F_ 384
#define M_ (B_*R_*G_)              // 32768 rows
static const size_t NBUF = (size_t)M_ * E_;       // 6291456 elems
static const size_t WPL  = 8 * (size_t)E_ * E_ + 2 * (size_t)E_ * F_;  // bf16/layer

typedef __attribute__((ext_vector_type(8))) short bf16x8;
typedef __attribute__((ext_vector_type(8))) unsigned short u16x8;
typedef __attribute__((ext_vector_type(4))) float f32x4;

__device__ __forceinline__ float gelu_exact(float x) {
    return 0.5f * x * (1.0f + erff(x * 0.7071067811865475f));
}
__device__ __forceinline__ unsigned short f2bf(float f) {
    __hip_bfloat16 h = __float2bfloat16(f);
    return *(unsigned short*)&h;
}
__device__ __forceinline__ float bf2f(unsigned short h) {
    union { unsigned u; float f; } v; v.u = ((unsigned)h) << 16; return v.f;
}
__device__ __forceinline__ bf16x8 mk8(unsigned long long lo, unsigned long long hi) {
    union { unsigned long long q[2]; bf16x8 v; } u;
    u.q[0] = lo; u.q[1] = hi; return u.v;
}

// ---- one-shot: transpose+convert all weights to Wt[N][K] bf16.
// Scale folds: Wq1 *= 1/sqrt(D); Wq2 *= log2(e)/sqrt(D)  (attn2 runs in exp2 domain).
__global__ __launch_bounds__(256)
void k_convw_all(const float* __restrict__ Wq1, const float* __restrict__ Wk1,
                 const float* __restrict__ Wv1, const float* __restrict__ Wo1,
                 const float* __restrict__ Wq2, const float* __restrict__ Wk2,
                 const float* __restrict__ Wv2, const float* __restrict__ Wo2,
                 const float* __restrict__ W1,  const float* __restrict__ W2,
                 unsigned short* __restrict__ Wt)
{
    const int t = blockIdx.x;
    const int layer = t / 432;
    const int r = t % 432;
    const float* src; unsigned short* dst; int K, N; float scale = 1.f; int tile;
    if (r < 288) {
        const int w = r / 36; tile = r % 36; K = E_; N = E_;
        const float* tab[8] = {Wq1, Wk1, Wv1, Wo1, Wq2, Wk2, Wv2, Wo2};
        src = tab[w] + (size_t)layer * E_ * E_;
        dst = Wt + (size_t)layer * WPL + (size_t)w * E_ * E_;
        if (w == 0) scale = 0.17677669529663687f;                       // 1/sqrt(32)
        if (w == 4) scale = 0.17677669529663687f * 1.4426950408889634f; // log2e/sqrt(32)
    } else if (r < 360) {
        tile = r - 288; K = E_; N = F_;
        src = W1 + (size_t)layer * E_ * F_;
        dst = Wt + (size_t)layer * WPL + 8 * (size_t)E_ * E_;
    } else {
        tile = r - 360; K = F_; N = E_;
        src = W2 + (size_t)layer * E_ * F_;
        dst = Wt + (size_t)layer * WPL + 8 * (size_t)E_ * E_ + (size_t)E_ * F_;
    }
    const int ntx = N / 32;
    const int kb = (tile / ntx) * 32, nb = (tile % ntx) * 32;
    __shared__ float tl[32][33];
    const int tx = threadIdx.x & 31, ty = threadIdx.x >> 5;
    for (int i2 = 0; i2 < 32; i2 += 8)
        tl[ty + i2][tx] = src[(size_t)(kb + ty + i2) * N + nb + tx];
    __syncthreads();
    for (int i2 = 0; i2 < 32; i2 += 8)
        dst[(size_t)(nb + ty + i2) * K + kb + tx] = f2bf(tl[tx][ty + i2] * scale);
}

// ---- MFMA GEMM, tile 64 x 192, BK=32, 4 waves, reg-prefetch pipeline (R8 form).
// EPI: 0 = store bf16 at [m][n0+n], ldc; 1 = gelu -> bf16, ldc.
template<bool ABF16, int EPI>
__global__ __launch_bounds__(256)
void k_gemm_mfma(const void* __restrict__ Ap, const unsigned short* __restrict__ Wt,
                 void* __restrict__ Cp, int ldc, int K)
{
    __shared__ unsigned short As[64][40];
    __shared__ unsigned short Bs[192][40];
    const int m0 = blockIdx.x * 64;
    const int n0 = blockIdx.y * 192;
    const int tid = threadIdx.x;
    const int w = tid >> 6, lane = tid & 63, l15 = lane & 15, g = lane >> 4;
    const int arow = tid >> 2, akoff = (tid & 3) << 3;
    f32x4 acc[4][3];
#pragma unroll
    for (int mt = 0; mt < 4; ++mt)
#pragma unroll
        for (int nt = 0; nt < 3; ++nt)
#pragma unroll
            for (int r2 = 0; r2 < 4; ++r2) acc[mt][nt][r2] = 0.f;
    const int nK = K >> 5;

    float4 ax, ay; u16x8 av; u16x8 bv0, bv1, bv2;
    auto gload = [&](int k0) {
        if (ABF16) {
            av = *(const u16x8*)((const unsigned short*)Ap + (size_t)(m0 + arow) * K + k0 + akoff);
        } else {
            const float* ap = (const float*)Ap + (size_t)(m0 + arow) * K + k0 + akoff;
            ax = *(const float4*)ap; ay = *(const float4*)(ap + 4);
        }
        bv0 = *(const u16x8*)(Wt + (size_t)(n0 + arow      ) * K + k0 + akoff);
        bv1 = *(const u16x8*)(Wt + (size_t)(n0 + arow +  64) * K + k0 + akoff);
        bv2 = *(const u16x8*)(Wt + (size_t)(n0 + arow + 128) * K + k0 + akoff);
    };
    auto swrite = [&]() {
        u16x8 aw;
        if (ABF16) aw = av;
        else {
            aw[0] = f2bf(ax.x); aw[1] = f2bf(ax.y); aw[2] = f2bf(ax.z); aw[3] = f2bf(ax.w);
            aw[4] = f2bf(ay.x); aw[5] = f2bf(ay.y); aw[6] = f2bf(ay.z); aw[7] = f2bf(ay.w);
        }
        *(u16x8*)&As[arow][akoff] = aw;
        *(u16x8*)&Bs[arow][akoff] = bv0;
        *(u16x8*)&Bs[arow + 64][akoff] = bv1;
        *(u16x8*)&Bs[arow + 128][akoff] = bv2;
    };

    gload(0);
    for (int kc = 0; kc < nK; ++kc) {
        __syncthreads();
        swrite();
        __syncthreads();
        if (kc + 1 < nK) gload((kc + 1) << 5);
        bf16x8 af[4], bfr[3];
#pragma unroll
        for (int mt = 0; mt < 4; ++mt) af[mt] = *(const bf16x8*)&As[mt * 16 + l15][g * 8];
#pragma unroll
        for (int nt = 0; nt < 3; ++nt) bfr[nt] = *(const bf16x8*)&Bs[w * 48 + nt * 16 + l15][g * 8];
#pragma unroll
        for (int mt = 0; mt < 4; ++mt)
#pragma unroll
            for (int nt = 0; nt < 3; ++nt)
                acc[mt][nt] = __builtin_amdgcn_mfma_f32_16x16x32_bf16(af[mt], bfr[nt], acc[mt][nt], 0, 0, 0);
    }

#pragma unroll
    for (int mt = 0; mt < 4; ++mt)
#pragma unroll
        for (int r2 = 0; r2 < 4; ++r2) {
            const int m = m0 + mt * 16 + g * 4 + r2;
#pragma unroll
            for (int nt = 0; nt < 3; ++nt) {
                const int n = w * 48 + nt * 16 + l15;
                float v = acc[mt][nt][r2];
                if (EPI == 1) v = gelu_exact(v);
                ((unsigned short*)Cp)[(size_t)m * ldc + n0 + n] = f2bf(v);
            }
        }
}

// ---- MFMA GEMM + residual + row-RMSNorm, tile 32 x 192, 4 waves, grid M/32.
// EPI: 2 = ->bf16, transpose X->XR; 3 = ->bf16, XR->X; 4 = ->f32; 5 = ->bf16.
template<bool RESBF16, int EPI>
__global__ __launch_bounds__(256)
void k_gemm_rms32(const unsigned short* __restrict__ Ap, const unsigned short* __restrict__ Wt,
                  const void* __restrict__ Resp, const float* __restrict__ gvec,
                  void* __restrict__ Cp, int K)
{
    __shared__ unsigned short As[32][40];
    __shared__ unsigned short Bs[192][40];
    __shared__ float ss_red[4][16];
    const int m0 = blockIdx.x * 32;
    const int tid = threadIdx.x;
    const int w = tid >> 6, lane = tid & 63, l15 = lane & 15, g = lane >> 4;
    const int mt = w & 1, nh = w >> 1;
    const int arow = tid >> 2, akoff = (tid & 3) << 3;
    f32x4 acc[6];
#pragma unroll
    for (int nt = 0; nt < 6; ++nt)
#pragma unroll
        for (int r2 = 0; r2 < 4; ++r2) acc[nt][r2] = 0.f;
    const int nK = K >> 5;

    u16x8 av, bv0, bv1, bv2;
    auto gload = [&](int k0) {
        if (tid < 128)
            av = *(const u16x8*)(Ap + (size_t)(m0 + arow) * K + k0 + akoff);
        bv0 = *(const u16x8*)(Wt + (size_t)(arow      ) * K + k0 + akoff);
        bv1 = *(const u16x8*)(Wt + (size_t)(arow +  64) * K + k0 + akoff);
        bv2 = *(const u16x8*)(Wt + (size_t)(arow + 128) * K + k0 + akoff);
    };
    auto swrite = [&]() {
        if (tid < 128) *(u16x8*)&As[arow][akoff] = av;
        *(u16x8*)&Bs[arow][akoff] = bv0;
        *(u16x8*)&Bs[arow + 64][akoff] = bv1;
        *(u16x8*)&Bs[arow + 128][akoff] = bv2;
    };

    gload(0);
    for (int kc = 0; kc < nK; ++kc) {
        __syncthreads();
        swrite();
        __syncthreads();
        if (kc + 1 < nK) gload((kc + 1) << 5);
        bf16x8 af = *(const bf16x8*)&As[mt * 16 + l15][g * 8];
        bf16x8 bfr[6];
#pragma unroll
        for (int nt = 0; nt < 6; ++nt) bfr[nt] = *(const bf16x8*)&Bs[nh * 96 + nt * 16 + l15][g * 8];
#pragma unroll
        for (int nt = 0; nt < 6; ++nt)
            acc[nt] = __builtin_amdgcn_mfma_f32_16x16x32_bf16(af, bfr[nt], acc[nt], 0, 0, 0);
    }

    float ssp[4] = {0.f, 0.f, 0.f, 0.f};
#pragma unroll
    for (int r2 = 0; r2 < 4; ++r2) {
        const int m = m0 + mt * 16 + g * 4 + r2;
#pragma unroll
        for (int nt = 0; nt < 6; ++nt) {
            const int n = nh * 96 + nt * 16 + l15;
            float rres = RESBF16 ? bf2f(((const unsigned short*)Resp)[(size_t)m * E_ + n])
                                 : ((const float*)Resp)[(size_t)m * E_ + n];
            float v = acc[nt][r2] + rres;
            acc[nt][r2] = v;
            ssp[r2] += v * v;
        }
    }
#pragma unroll
    for (int off = 1; off < 16; off <<= 1)
#pragma unroll
        for (int r2 = 0; r2 < 4; ++r2)
            ssp[r2] += __shfl_xor(ssp[r2], off);
    if (l15 == 0) {
#pragma unroll
        for (int r2 = 0; r2 < 4; ++r2)
            ss_red[w][g * 4 + r2] = ssp[r2];
    }
    __syncthreads();
#pragma unroll
    for (int r2 = 0; r2 < 4; ++r2) {
        const int lr = g * 4 + r2;
        const float ss = ss_red[mt][lr] + ss_red[2 + mt][lr];
        const float inv = rsqrtf(ss * (1.0f / 192.0f) + 1.1920929e-07f);
        const int m = m0 + mt * 16 + lr;
        size_t orow;
        if (EPI == 2) {        // X -> XR
            const int b = m >> 13, rr = (m >> 3) & 1023, gg = m & 7;
            orow = (((size_t)b * G_ + gg) << 10) + rr;
        } else if (EPI == 3) { // XR -> X
            const int b = m >> 13, gg = (m >> 10) & 7, rr = m & 1023;
            orow = ((((size_t)b << 10) + rr) << 3) + gg;
        } else {
            orow = m;
        }
#pragma unroll
        for (int nt = 0; nt < 6; ++nt) {
            const int n = nh * 96 + nt * 16 + l15;
            const float v = acc[nt][r2] * inv * gvec[n];
            if (EPI == 4) ((float*)Cp)[orow * E_ + n] = v;
            else          ((unsigned short*)Cp)[orow * E_ + n] = f2bf(v);
        }
    }
}

// ---- Fused feature-attention block v5 (R17 best): per-wave-private B slices
// with XOR-swizzled UNPADDED layout ([rows][32], block kb at kb^(row&3)):
// uniform bank depth 8 on writes and reads; LDS 50.2 KB => 3 blocks/CU.
// 5 barriers total.
template<bool AF32>
__global__ __launch_bounds__(256)
void k_featblock(const void* __restrict__ Xin, const unsigned short* __restrict__ Wqkv,
                 const unsigned short* __restrict__ Wo, const float* __restrict__ gvec,
                 unsigned short* __restrict__ Ynb)
{
    __shared__ __align__(16) unsigned short raw[18688];      // 37376 B (QKVl is max user)
    __shared__ __align__(16) unsigned short AsTl[32][200];   // 12800 B: A (ph1) -> Tl (ph2/3)

    unsigned short (*QKVl)[584] = (unsigned short (*)[584])raw;
    const int m0 = blockIdx.x * 32;
    const int tid = threadIdx.x;
    const int w = tid >> 6, lane = tid & 63, l15 = lane & 15, g = lane >> 4;

    // ---- stage A once (32 x 192, coalesced) ----
#pragma unroll
    for (int j = 0; j < 3; ++j) {
        const int v = tid + 256 * j;          // 0..767
        const int row = v / 24, ch = v % 24;  // 24 chunks of 8 elems per row
        u16x8 aw;
        if (AF32) {
            const float* ap = (const float*)Xin + (size_t)(m0 + row) * E_ + ch * 8;
            float4 x = *(const float4*)ap, y = *(const float4*)(ap + 4);
            aw[0] = f2bf(x.x); aw[1] = f2bf(x.y); aw[2] = f2bf(x.z); aw[3] = f2bf(x.w);
            aw[4] = f2bf(y.x); aw[5] = f2bf(y.y); aw[6] = f2bf(y.z); aw[7] = f2bf(y.w);
        } else {
            aw = *(const u16x8*)((const unsigned short*)Xin + (size_t)(m0 + row) * E_ + ch * 8);
        }
        *(u16x8*)&AsTl[row][ch * 8] = aw;
    }
    __syncthreads();   // B1: A visible to all waves

    // ---- phase 1: QKV = A @ Wqkv^T, per-wave swizzled B slices, no barriers ----
    f32x4 acc[2][9];
#pragma unroll
    for (int mt = 0; mt < 2; ++mt)
#pragma unroll
        for (int nt = 0; nt < 9; ++nt)
#pragma unroll
            for (int r2 = 0; r2 < 4; ++r2) acc[mt][nt][r2] = 0.f;

    unsigned short* slice1 = raw + w * 4608;          // [144][32] swizzled
    u16x8 bv[9];
    auto gload1 = [&](int k0) {
#pragma unroll
        for (int j = 0; j < 9; ++j) {
            const int v = lane + 64 * j;
            bv[j] = *(const u16x8*)(Wqkv + (size_t)(w * 144 + (v >> 2)) * E_ + k0 + ((v & 3) << 3));
        }
    };
    auto swrite1 = [&]() {
#pragma unroll
        for (int j = 0; j < 9; ++j) {
            const int v = lane + 64 * j;
            const int row = v >> 2;
            const int pos = (v & 3) ^ (row & 3);      // XOR swizzle
            *(u16x8*)&slice1[row * 32 + pos * 8] = bv[j];
        }
    };
    const int rb1 = g ^ (l15 & 3);                    // read-side swizzled block

    gload1(0);
    swrite1();
    gload1(32);
#pragma unroll
    for (int kc = 0; kc < 6; ++kc) {
        const int k0 = kc << 5;
        bf16x8 af0 = *(const bf16x8*)&AsTl[l15][k0 + g * 8];
        bf16x8 af1 = *(const bf16x8*)&AsTl[16 + l15][k0 + g * 8];
        bf16x8 bfr[9];
#pragma unroll
        for (int nt = 0; nt < 9; ++nt)
            bfr[nt] = *(const bf16x8*)&slice1[(nt * 16 + l15) * 32 + rb1 * 8];
#pragma unroll
        for (int nt = 0; nt < 9; ++nt) {
            acc[0][nt] = __builtin_amdgcn_mfma_f32_16x16x32_bf16(af0, bfr[nt], acc[0][nt], 0, 0, 0);
            acc[1][nt] = __builtin_amdgcn_mfma_f32_16x16x32_bf16(af1, bfr[nt], acc[1][nt], 0, 0, 0);
        }
        if (kc + 1 < 6) swrite1();                 // bv holds kc+1 (in-order LDS)
        if (kc + 2 < 6) gload1((kc + 2) << 5);
    }
    __syncthreads();   // B2: all waves' Bq reads done before QKVl overlay

    // spill QKV to QKVl (wave w writes its 144-col slice of all 32 rows)
#pragma unroll
    for (int mt = 0; mt < 2; ++mt)
#pragma unroll
        for (int r2 = 0; r2 < 4; ++r2)
#pragma unroll
            for (int nt = 0; nt < 9; ++nt)
                QKVl[mt * 16 + g * 4 + r2][w * 144 + nt * 16 + l15] = f2bf(acc[mt][nt][r2]);

    // prefetch phase-3 chunk-0 weights (latency hides under attn1)
    u16x8 bo[3];
    auto gload3 = [&](int k0) {
#pragma unroll
        for (int j = 0; j < 3; ++j) {
            const int v = lane + 64 * j;
            bo[j] = *(const u16x8*)(Wo + (size_t)(w * 48 + (v >> 2)) * E_ + k0 + ((v & 3) << 3));
        }
    };
    gload3(0);
    __syncthreads();   // B3: QKVl complete

    // ---- phase 2: attn1 (wave w = seq w; lane = i*8+j over G=8) ----
    {
        const int i = lane >> 3, j = lane & 7;
        const int r0 = w * 8;
#pragma unroll
        for (int h = 0; h < 6; ++h) {
            float s = 0.f;
#pragma unroll
            for (int d8 = 0; d8 < 4; ++d8) {
                u16x8 qv = *(const u16x8*)&QKVl[r0 + i][h * 32 + d8 * 8];
                u16x8 kv = *(const u16x8*)&QKVl[r0 + j][192 + h * 32 + d8 * 8];
#pragma unroll
                for (int e = 0; e < 8; ++e) s += bf2f(qv[e]) * bf2f(kv[e]);
            }
            float mx = s;
#pragma unroll
            for (int off = 1; off < 8; off <<= 1) mx = fmaxf(mx, __shfl_xor(mx, off));
            float p = __expf(s - mx);
            float sum = p;
#pragma unroll
            for (int off = 1; off < 8; off <<= 1) sum += __shfl_xor(sum, off);
            p /= sum;
            const int base = lane & ~7;
            float o0 = 0.f, o1 = 0.f, o2 = 0.f, o3 = 0.f;
#pragma unroll
            for (int jj = 0; jj < 8; ++jj) {
                float pj = __shfl(p, base + jj);
                ushort4 vv = *(const ushort4*)&QKVl[r0 + jj][384 + h * 32 + j * 4];
                o0 += pj * bf2f(vv.x); o1 += pj * bf2f(vv.y);
                o2 += pj * bf2f(vv.z); o3 += pj * bf2f(vv.w);
            }
            ushort4 ov; ov.x = f2bf(o0); ov.y = f2bf(o1); ov.z = f2bf(o2); ov.w = f2bf(o3);
            *(ushort4*)&AsTl[r0 + i][h * 32 + j * 4] = ov;   // Tl overlays A
        }
    }

    // preload epilogue residual (hides under phase 3)
    float rv[2][4][3];
#pragma unroll
    for (int mt = 0; mt < 2; ++mt)
#pragma unroll
        for (int r2 = 0; r2 < 4; ++r2) {
            const int m = m0 + mt * 16 + g * 4 + r2;
#pragma unroll
            for (int nt = 0; nt < 3; ++nt) {
                const int n = w * 48 + nt * 16 + l15;
                rv[mt][r2][nt] = AF32 ? ((const float*)Xin)[(size_t)m * E_ + n]
                                      : bf2f(((const unsigned short*)Xin)[(size_t)m * E_ + n]);
            }
        }
    __syncthreads();   // B4: Tl complete; QKVl reads done before Bo overlay

    // ---- phase 3: T @ wo1^T, per-wave swizzled Bo slices, no barriers ----
    unsigned short* slice3 = raw + w * 1536;          // [48][32] swizzled
    f32x4 acc2[2][3];
#pragma unroll
    for (int mt = 0; mt < 2; ++mt)
#pragma unroll
        for (int nt = 0; nt < 3; ++nt)
#pragma unroll
            for (int r2 = 0; r2 < 4; ++r2) acc2[mt][nt][r2] = 0.f;

    auto swrite3 = [&]() {
#pragma unroll
        for (int j = 0; j < 3; ++j) {
            const int v = lane + 64 * j;
            const int row = v >> 2;
            const int pos = (v & 3) ^ (row & 3);
            *(u16x8*)&slice3[row * 32 + pos * 8] = bo[j];
        }
    };
    swrite3();
    gload3(32);
#pragma unroll
    for (int kc = 0; kc < 6; ++kc) {
        const int k0 = kc << 5;
        bf16x8 af0 = *(const bf16x8*)&AsTl[l15][k0 + g * 8];
        bf16x8 af1 = *(const bf16x8*)&AsTl[16 + l15][k0 + g * 8];
        bf16x8 bfr[3];
#pragma unroll
        for (int nt = 0; nt < 3; ++nt)
            bfr[nt] = *(const bf16x8*)&slice3[(nt * 16 + l15) * 32 + rb1 * 8];
#pragma unroll
        for (int nt = 0; nt < 3; ++nt) {
            acc2[0][nt] = __builtin_amdgcn_mfma_f32_16x16x32_bf16(af0, bfr[nt], acc2[0][nt], 0, 0, 0);
            acc2[1][nt] = __builtin_amdgcn_mfma_f32_16x16x32_bf16(af1, bfr[nt], acc2[1][nt], 0, 0, 0);
        }
        if (kc + 1 < 6) swrite3();
        if (kc + 2 < 6) gload3((kc + 2) << 5);
    }

    // ---- epilogue: +res(preloaded), row-RMS*g1, transpose X->XR ----
    float* S = (float*)(raw + 6400);   // beyond Bo slices (elems 0..6143)
    float ssp[2][4] = {};
#pragma unroll
    for (int mt = 0; mt < 2; ++mt)
#pragma unroll
        for (int r2 = 0; r2 < 4; ++r2) {
#pragma unroll
            for (int nt = 0; nt < 3; ++nt) {
                float v = acc2[mt][nt][r2] + rv[mt][r2][nt];
                acc2[mt][nt][r2] = v;
                ssp[mt][r2] += v * v;
            }
        }
#pragma unroll
    for (int off = 1; off < 16; off <<= 1)
#pragma unroll
        for (int mt = 0; mt < 2; ++mt)
#pragma unroll
            for (int r2 = 0; r2 < 4; ++r2)
                ssp[mt][r2] += __shfl_xor(ssp[mt][r2], off);
    if (l15 == 0) {
#pragma unroll
        for (int mt = 0; mt < 2; ++mt)
#pragma unroll
            for (int r2 = 0; r2 < 4; ++r2)
                S[w * 32 + mt * 16 + g * 4 + r2] = ssp[mt][r2];
    }
    __syncthreads();   // B5
#pragma unroll
    for (int mt = 0; mt < 2; ++mt)
#pragma unroll
        for (int r2 = 0; r2 < 4; ++r2) {
            const int row = mt * 16 + g * 4 + r2;
            const float ss = S[row] + S[32 + row] + S[64 + row] + S[96 + row];
            const float inv = rsqrtf(ss * (1.0f / 192.0f) + 1.1920929e-07f);
            const int m = m0 + row;
            const int b = m >> 13, rr = (m >> 3) & 1023, gg = m & 7;
            const size_t orow = (((size_t)(b * G_ + gg)) << 10) + rr;
#pragma unroll
            for (int nt = 0; nt < 3; ++nt) {
                const int n = w * 48 + nt * 16 + l15;
                Ynb[orow * E_ + n] = f2bf(acc2[mt][nt][r2] * inv * gvec[n]);
            }
        }
}

// ---- Row attention (R14 form, NO max-tracking): scores in exp2 domain are
// O(+-10), so P = exp2(s) with implicit max 0 cannot overflow; ones-row MFMA
// denominator normalizes exactly.
__global__ __launch_bounds__(256)
void k_attn2(const unsigned short* __restrict__ QKV, unsigned short* __restrict__ T,
             const int* __restrict__ sep_ptr)
{
    __shared__ __align__(16) unsigned short K_lds[64][40];
    __shared__ __align__(16) unsigned short V_lds[2048];   // [dg(2)][kblk(16)][4][16]

    const int sep = *sep_ptr;
    const int bid = blockIdx.x;
    const int sh = ((bid >> 7) << 3) | (bid & 7);   // same (s,h) => same XCD
    const int qtile = (bid >> 3) & 15;
    const int s = sh / H_, h = sh % H_;
    const int q0 = qtile * 64;

    const int tid = threadIdx.x;
    const int w = tid >> 6;
    const int lane = tid & 63;
    const int l15 = lane & 15;
    const int g = lane >> 4;

    const int qrow = q0 + w * 16 + l15;
    u16x8 qf = *(const u16x8*)(QKV + ((size_t)s * R_ + qrow) * 576 + h * D_ + g * 8);

    u16x8 onesu;
#pragma unroll
    for (int e = 0; e < 8; ++e) onesu[e] = 0x3F80;  // bf16 1.0
    const bf16x8 onesf = (bf16x8)onesu;

    const bool lo = (q0 < sep);
    const bool hi = (q0 + 64 > sep);
    const int npass = (lo && hi) ? 2 : 1;
    const int nChunk = (sep + 63) >> 6;

    const int skey = tid >> 2;
    const int sg   = tid & 3;
    const int vst = ((sg >> 1) * 16 + (skey >> 2)) * 64 + (skey & 3) * 16 + (sg & 1) * 8;
    const unsigned vaddr = (unsigned)(size_t)&V_lds[0] + (unsigned)(g * 128 + l15 * 2);

    for (int pass = 0; pass < npass; ++pass) {
        const int hk = (pass == 0) ? (lo ? h : 0) : 0;
        const unsigned short* Kb = QKV + (size_t)s * R_ * 576 + 192 + hk * D_;
        const unsigned short* Vb = QKV + (size_t)s * R_ * 576 + 384 + hk * D_;

        f32x4 o0 = {0.f, 0.f, 0.f, 0.f};
        f32x4 o1 = {0.f, 0.f, 0.f, 0.f};
        f32x4 o2 = {0.f, 0.f, 0.f, 0.f};   // ones-row: running sum of P

        u16x8 kv_k = *(const u16x8*)(Kb + (size_t)skey * 576 + sg * 8);
        u16x8 kv_v = *(const u16x8*)(Vb + (size_t)skey * 576 + sg * 8);

        for (int kc = 0; kc < nChunk; ++kc) {
            const int kbase = kc * 64;
            const bool full = (kbase + 64 <= sep);
            __syncthreads();
            *(u16x8*)&K_lds[skey][sg * 8] = kv_k;
            *(u16x8*)&V_lds[vst] = kv_v;
            __syncthreads();
            if (kc + 1 < nChunk) {
                kv_k = *(const u16x8*)(Kb + (size_t)(kbase + 64 + skey) * 576 + sg * 8);
                kv_v = *(const u16x8*)(Vb + (size_t)(kbase + 64 + skey) * 576 + sg * 8);
            }

            f32x4 sc[4];
            const f32x4 zf = {0.f, 0.f, 0.f, 0.f};
            __builtin_amdgcn_s_setprio(1);
#pragma unroll
            for (int t = 0; t < 4; ++t) {
                bf16x8 a = *(const bf16x8*)&K_lds[t * 16 + l15][g * 8];
                sc[t] = __builtin_amdgcn_mfma_f32_16x16x32_bf16(a, (bf16x8)qf, zf, 0, 0, 0);
            }
            __builtin_amdgcn_s_setprio(0);
            if (!full) {
#pragma unroll
                for (int t = 0; t < 4; ++t)
#pragma unroll
                    for (int r = 0; r < 4; ++r)
                        if (kbase + t * 16 + g * 4 + r >= sep) sc[t][r] = -1e30f;
            }
            // P = exp2(s) directly (implicit max = 0); pack to B-fragments.
            bf16x8 pb0, pb1;
            {
                u16x8 p0, p1;
#pragma unroll
                for (int r = 0; r < 4; ++r) {
                    p0[r]     = f2bf(exp2f(sc[0][r]));
                    p0[4 + r] = f2bf(exp2f(sc[1][r]));
                    p1[r]     = f2bf(exp2f(sc[2][r]));
                    p1[4 + r] = f2bf(exp2f(sc[3][r]));
                }
                pb0 = (bf16x8)p0; pb1 = (bf16x8)p1;
            }
            unsigned long long t0, t1, t2, t3, t4, t5, t6, t7;
            asm volatile(
                "ds_read_b64_tr_b16 %0, %8 offset:0\n\t"
                "ds_read_b64_tr_b16 %1, %8 offset:512\n\t"
                "ds_read_b64_tr_b16 %2, %8 offset:1024\n\t"
                "ds_read_b64_tr_b16 %3, %8 offset:1536\n\t"
                "ds_read_b64_tr_b16 %4, %8 offset:2048\n\t"
                "ds_read_b64_tr_b16 %5, %8 offset:2560\n\t"
                "ds_read_b64_tr_b16 %6, %8 offset:3072\n\t"
                "ds_read_b64_tr_b16 %7, %8 offset:3584\n\t"
                "s_waitcnt lgkmcnt(0)"
                : "=&v"(t0), "=&v"(t1), "=&v"(t2), "=&v"(t3),
                  "=&v"(t4), "=&v"(t5), "=&v"(t6), "=&v"(t7)
                : "v"(vaddr)
                : "memory");
            __builtin_amdgcn_sched_barrier(0);
            __builtin_amdgcn_s_setprio(1);
            o0 = __builtin_amdgcn_mfma_f32_16x16x32_bf16(mk8(t0, t1), pb0, o0, 0, 0, 0);
            o1 = __builtin_amdgcn_mfma_f32_16x16x32_bf16(mk8(t4, t5), pb0, o1, 0, 0, 0);
            o2 = __builtin_amdgcn_mfma_f32_16x16x32_bf16(onesf,       pb0, o2, 0, 0, 0);
            o0 = __builtin_amdgcn_mfma_f32_16x16x32_bf16(mk8(t2, t3), pb1, o0, 0, 0, 0);
            o1 = __builtin_amdgcn_mfma_f32_16x16x32_bf16(mk8(t6, t7), pb1, o1, 0, 0, 0);
            o2 = __builtin_amdgcn_mfma_f32_16x16x32_bf16(onesf,       pb1, o2, 0, 0, 0);
            __builtin_amdgcn_s_setprio(0);
        }

        const bool valid = (npass == 1) || (pass == 0 ? (qrow < sep) : (qrow >= sep));
        if (valid) {
            const float inv = 1.f / o2[0];
            unsigned short* tp = T + ((size_t)s * R_ + qrow) * E_ + h * D_;
            ushort4 v0, v1;
            v0.x = f2bf(o0[0] * inv); v0.y = f2bf(o0[1] * inv);
            v0.z = f2bf(o0[2] * inv); v0.w = f2bf(o0[3] * inv);
            v1.x = f2bf(o1[0] * inv); v1.y = f2bf(o1[1] * inv);
            v1.z = f2bf(o1[2] * inv); v1.w = f2bf(o1[3] * inv);
            *(ushort4*)(tp + g * 4)      = v0;
            *(ushort4*)(tp + 16 + g * 4) = v1;
        }
    }
}

extern "C" void kernel_launch(void* const* d_in, const int* in_sizes, int n_in,
                              void* d_out, int out_size, void* d_ws, size_t ws_size,
                              hipStream_t stream) {
    const float* hidden = (const float*)d_in[0];
    const float* Wq1 = (const float*)d_in[1];
    const float* Wk1 = (const float*)d_in[2];
    const float* Wv1 = (const float*)d_in[3];
    const float* Wo1 = (const float*)d_in[4];
    const float* Wq2 = (const float*)d_in[5];
    const float* Wk2 = (const float*)d_in[6];
    const float* Wv2 = (const float*)d_in[7];
    const float* Wo2 = (const float*)d_in[8];
    const float* W1  = (const float*)d_in[9];
    const float* W2  = (const float*)d_in[10];
    const float* g1  = (const float*)d_in[11];
    const float* g2  = (const float*)d_in[12];
    const float* g3  = (const float*)d_in[13];
    const int*   sep = (const int*)d_in[14];

    float* Xout = (float*)d_out;                    // final f32 X-layout output
    unsigned short* ws = (unsigned short*)d_ws;
    unsigned short* QKVb = ws;                      // [M][576] bf16 (aliases H1 [M][384])
    unsigned short* Tb   = QKVb + (size_t)M_ * 576;
    unsigned short* Ynb  = Tb + NBUF;               // rms-g1 output, XR layout
    unsigned short* Xcb  = Ynb + NBUF;              // rms-g2 output, X layout
    unsigned short* Xb   = Xcb + NBUF;              // inter-layer residual (layers 0-2)
    unsigned short* Wt   = Xb + NBUF;
    unsigned short* H1b  = QKVb;

    const dim3 blk(256);
    const dim3 gQKV(M_ / 64, 3);
    const dim3 gW1(M_ / 64, 2);
    const dim3 g32(M_ / 32);                        // 1024 blocks
    const dim3 gA2(32 * H_ * 16);

    k_convw_all<<<dim3(432 * L_), blk, 0, stream>>>(Wq1, Wk1, Wv1, Wo1, Wq2, Wk2, Wv2, Wo2, W1, W2, Wt);

    for (int i = 0; i < L_; ++i) {
        unsigned short* wl = Wt + (size_t)i * WPL;
        const unsigned short* wqkv1 = wl;
        const unsigned short* wo1   = wl + 3 * (size_t)E_ * E_;
        const unsigned short* wqkv2 = wl + 4 * (size_t)E_ * E_;
        const unsigned short* wo2   = wl + 7 * (size_t)E_ * E_;
        const unsigned short* w1    = wl + 8 * (size_t)E_ * E_;
        const unsigned short* w2    = wl + 8 * (size_t)E_ * E_ + (size_t)E_ * F_;
        const float* g1i = g1 + (size_t)i * E_;
        const float* g2i = g2 + (size_t)i * E_;
        const float* g3i = g3 + (size_t)i * E_;

        // --- fused feature-attention block: X/hidden -> Ynb (XR) ---
        if (i == 0)
            k_featblock<true><<<g32, blk, 0, stream>>>(hidden, wqkv1, wo1, g1i, Ynb);
        else
            k_featblock<false><<<g32, blk, 0, stream>>>(Xb, wqkv1, wo1, g1i, Ynb);
        // --- row attention block ---
        k_gemm_mfma<true, 0><<<gQKV, blk, 0, stream>>>(Ynb, wqkv2, QKVb, 576, E_);
        k_attn2<<<gA2, blk, 0, stream>>>(QKVb, Tb, sep);
        k_gemm_rms32<true, 3><<<g32, blk, 0, stream>>>(Tb, wo2, Ynb, g2i, Xcb, E_);
        // --- MLP block ---
        k_gemm_mfma<true, 1><<<gW1, blk, 0, stream>>>(Xcb, w1, H1b, F_, E_);
        if (i == L_ - 1)
            k_gemm_rms32<true, 4><<<g32, blk, 0, stream>>>(H1b, w2, Xcb, g3i, Xout, F_);
        else
            k_gemm_rms32<true, 5><<<g32, blk, 0, stream>>>(H1b, w2, Xcb, g3i, Xb, F_);
    }
}

// Round 20
// 586.381 us; speedup vs baseline: 1.0655x; 1.0363x over previous
//
#include <hip/hip_runtime.h>
#include <hip/hip_bf16.h>
#include <math.h>

#define B_ 4
#define R_ 1024
#define G_ 8
#define E_ 192
#define H_ 6
#define D_ 32
#define L_ 4
#define F_ 384
#define M_ (B_*R_*G_)              // 32768 rows
static const size_t NBUF = (size_t)M_ * E_;       // 6291456 elems
static const size_t WPL  = 8 * (size_t)E_ * E_ + 2 * (size_t)E_ * F_;  // bf16/layer

typedef __attribute__((ext_vector_type(8))) short bf16x8;
typedef __attribute__((ext_vector_type(8))) unsigned short u16x8;
typedef __attribute__((ext_vector_type(4))) float f32x4;

__device__ __forceinline__ float gelu_exact(float x) {
    return 0.5f * x * (1.0f + erff(x * 0.7071067811865475f));
}
__device__ __forceinline__ unsigned short f2bf(float f) {
    __hip_bfloat16 h = __float2bfloat16(f);
    return *(unsigned short*)&h;
}
__device__ __forceinline__ float bf2f(unsigned short h) {
    union { unsigned u; float f; } v; v.u = ((unsigned)h) << 16; return v.f;
}
__device__ __forceinline__ bf16x8 mk8(unsigned long long lo, unsigned long long hi) {
    union { unsigned long long q[2]; bf16x8 v; } u;
    u.q[0] = lo; u.q[1] = hi; return u.v;
}

// ---- one-shot: transpose+convert all weights to Wt[N][K] bf16.
// Scale folds: Wq1 *= 1/sqrt(D); Wq2 *= log2(e)/sqrt(D)  (attn2 runs in exp2 domain).
__global__ __launch_bounds__(256)
void k_convw_all(const float* __restrict__ Wq1, const float* __restrict__ Wk1,
                 const float* __restrict__ Wv1, const float* __restrict__ Wo1,
                 const float* __restrict__ Wq2, const float* __restrict__ Wk2,
                 const float* __restrict__ Wv2, const float* __restrict__ Wo2,
                 const float* __restrict__ W1,  const float* __restrict__ W2,
                 unsigned short* __restrict__ Wt)
{
    const int t = blockIdx.x;
    const int layer = t / 432;
    const int r = t % 432;
    const float* src; unsigned short* dst; int K, N; float scale = 1.f; int tile;
    if (r < 288) {
        const int w = r / 36; tile = r % 36; K = E_; N = E_;
        const float* tab[8] = {Wq1, Wk1, Wv1, Wo1, Wq2, Wk2, Wv2, Wo2};
        src = tab[w] + (size_t)layer * E_ * E_;
        dst = Wt + (size_t)layer * WPL + (size_t)w * E_ * E_;
        if (w == 0) scale = 0.17677669529663687f;                       // 1/sqrt(32)
        if (w == 4) scale = 0.17677669529663687f * 1.4426950408889634f; // log2e/sqrt(32)
    } else if (r < 360) {
        tile = r - 288; K = E_; N = F_;
        src = W1 + (size_t)layer * E_ * F_;
        dst = Wt + (size_t)layer * WPL + 8 * (size_t)E_ * E_;
    } else {
        tile = r - 360; K = F_; N = E_;
        src = W2 + (size_t)layer * E_ * F_;
        dst = Wt + (size_t)layer * WPL + 8 * (size_t)E_ * E_ + (size_t)E_ * F_;
    }
    const int ntx = N / 32;
    const int kb = (tile / ntx) * 32, nb = (tile % ntx) * 32;
    __shared__ float tl[32][33];
    const int tx = threadIdx.x & 31, ty = threadIdx.x >> 5;
    for (int i2 = 0; i2 < 32; i2 += 8)
        tl[ty + i2][tx] = src[(size_t)(kb + ty + i2) * N + nb + tx];
    __syncthreads();
    for (int i2 = 0; i2 < 32; i2 += 8)
        dst[(size_t)(nb + ty + i2) * K + kb + tx] = f2bf(tl[tx][ty + i2] * scale);
}

// ---- MFMA GEMM, tile 64 x 192, BK=32, 4 waves, reg-prefetch pipeline (R8 form).
// EPI: 0 = store bf16 at [m][n0+n], ldc; 1 = gelu -> bf16, ldc.
template<bool ABF16, int EPI>
__global__ __launch_bounds__(256)
void k_gemm_mfma(const void* __restrict__ Ap, const unsigned short* __restrict__ Wt,
                 void* __restrict__ Cp, int ldc, int K)
{
    __shared__ unsigned short As[64][40];
    __shared__ unsigned short Bs[192][40];
    const int m0 = blockIdx.x * 64;
    const int n0 = blockIdx.y * 192;
    const int tid = threadIdx.x;
    const int w = tid >> 6, lane = tid & 63, l15 = lane & 15, g = lane >> 4;
    const int arow = tid >> 2, akoff = (tid & 3) << 3;
    f32x4 acc[4][3];
#pragma unroll
    for (int mt = 0; mt < 4; ++mt)
#pragma unroll
        for (int nt = 0; nt < 3; ++nt)
#pragma unroll
            for (int r2 = 0; r2 < 4; ++r2) acc[mt][nt][r2] = 0.f;
    const int nK = K >> 5;

    float4 ax, ay; u16x8 av; u16x8 bv0, bv1, bv2;
    auto gload = [&](int k0) {
        if (ABF16) {
            av = *(const u16x8*)((const unsigned short*)Ap + (size_t)(m0 + arow) * K + k0 + akoff);
        } else {
            const float* ap = (const float*)Ap + (size_t)(m0 + arow) * K + k0 + akoff;
            ax = *(const float4*)ap; ay = *(const float4*)(ap + 4);
        }
        bv0 = *(const u16x8*)(Wt + (size_t)(n0 + arow      ) * K + k0 + akoff);
        bv1 = *(const u16x8*)(Wt + (size_t)(n0 + arow +  64) * K + k0 + akoff);
        bv2 = *(const u16x8*)(Wt + (size_t)(n0 + arow + 128) * K + k0 + akoff);
    };
    auto swrite = [&]() {
        u16x8 aw;
        if (ABF16) aw = av;
        else {
            aw[0] = f2bf(ax.x); aw[1] = f2bf(ax.y); aw[2] = f2bf(ax.z); aw[3] = f2bf(ax.w);
            aw[4] = f2bf(ay.x); aw[5] = f2bf(ay.y); aw[6] = f2bf(ay.z); aw[7] = f2bf(ay.w);
        }
        *(u16x8*)&As[arow][akoff] = aw;
        *(u16x8*)&Bs[arow][akoff] = bv0;
        *(u16x8*)&Bs[arow + 64][akoff] = bv1;
        *(u16x8*)&Bs[arow + 128][akoff] = bv2;
    };

    gload(0);
    for (int kc = 0; kc < nK; ++kc) {
        __syncthreads();
        swrite();
        __syncthreads();
        if (kc + 1 < nK) gload((kc + 1) << 5);
        bf16x8 af[4], bfr[3];
#pragma unroll
        for (int mt = 0; mt < 4; ++mt) af[mt] = *(const bf16x8*)&As[mt * 16 + l15][g * 8];
#pragma unroll
        for (int nt = 0; nt < 3; ++nt) bfr[nt] = *(const bf16x8*)&Bs[w * 48 + nt * 16 + l15][g * 8];
#pragma unroll
        for (int mt = 0; mt < 4; ++mt)
#pragma unroll
            for (int nt = 0; nt < 3; ++nt)
                acc[mt][nt] = __builtin_amdgcn_mfma_f32_16x16x32_bf16(af[mt], bfr[nt], acc[mt][nt], 0, 0, 0);
    }

#pragma unroll
    for (int mt = 0; mt < 4; ++mt)
#pragma unroll
        for (int r2 = 0; r2 < 4; ++r2) {
            const int m = m0 + mt * 16 + g * 4 + r2;
#pragma unroll
            for (int nt = 0; nt < 3; ++nt) {
                const int n = w * 48 + nt * 16 + l15;
                float v = acc[mt][nt][r2];
                if (EPI == 1) v = gelu_exact(v);
                ((unsigned short*)Cp)[(size_t)m * ldc + n0 + n] = f2bf(v);
            }
        }
}

// ---- MFMA GEMM + residual + row-RMSNorm, tile 32 x 192, 4 waves, grid M/32.
// EPI: 2 = ->bf16, transpose X->XR; 3 = ->bf16, XR->X; 4 = ->f32; 5 = ->bf16.
template<bool RESBF16, int EPI>
__global__ __launch_bounds__(256)
void k_gemm_rms32(const unsigned short* __restrict__ Ap, const unsigned short* __restrict__ Wt,
                  const void* __restrict__ Resp, const float* __restrict__ gvec,
                  void* __restrict__ Cp, int K)
{
    __shared__ unsigned short As[32][40];
    __shared__ unsigned short Bs[192][40];
    __shared__ float ss_red[4][16];
    const int m0 = blockIdx.x * 32;
    const int tid = threadIdx.x;
    const int w = tid >> 6, lane = tid & 63, l15 = lane & 15, g = lane >> 4;
    const int mt = w & 1, nh = w >> 1;
    const int arow = tid >> 2, akoff = (tid & 3) << 3;
    f32x4 acc[6];
#pragma unroll
    for (int nt = 0; nt < 6; ++nt)
#pragma unroll
        for (int r2 = 0; r2 < 4; ++r2) acc[nt][r2] = 0.f;
    const int nK = K >> 5;

    u16x8 av, bv0, bv1, bv2;
    auto gload = [&](int k0) {
        if (tid < 128)
            av = *(const u16x8*)(Ap + (size_t)(m0 + arow) * K + k0 + akoff);
        bv0 = *(const u16x8*)(Wt + (size_t)(arow      ) * K + k0 + akoff);
        bv1 = *(const u16x8*)(Wt + (size_t)(arow +  64) * K + k0 + akoff);
        bv2 = *(const u16x8*)(Wt + (size_t)(arow + 128) * K + k0 + akoff);
    };
    auto swrite = [&]() {
        if (tid < 128) *(u16x8*)&As[arow][akoff] = av;
        *(u16x8*)&Bs[arow][akoff] = bv0;
        *(u16x8*)&Bs[arow + 64][akoff] = bv1;
        *(u16x8*)&Bs[arow + 128][akoff] = bv2;
    };

    gload(0);
    for (int kc = 0; kc < nK; ++kc) {
        __syncthreads();
        swrite();
        __syncthreads();
        if (kc + 1 < nK) gload((kc + 1) << 5);
        bf16x8 af = *(const bf16x8*)&As[mt * 16 + l15][g * 8];
        bf16x8 bfr[6];
#pragma unroll
        for (int nt = 0; nt < 6; ++nt) bfr[nt] = *(const bf16x8*)&Bs[nh * 96 + nt * 16 + l15][g * 8];
#pragma unroll
        for (int nt = 0; nt < 6; ++nt)
            acc[nt] = __builtin_amdgcn_mfma_f32_16x16x32_bf16(af, bfr[nt], acc[nt], 0, 0, 0);
    }

    float ssp[4] = {0.f, 0.f, 0.f, 0.f};
#pragma unroll
    for (int r2 = 0; r2 < 4; ++r2) {
        const int m = m0 + mt * 16 + g * 4 + r2;
#pragma unroll
        for (int nt = 0; nt < 6; ++nt) {
            const int n = nh * 96 + nt * 16 + l15;
            float rres = RESBF16 ? bf2f(((const unsigned short*)Resp)[(size_t)m * E_ + n])
                                 : ((const float*)Resp)[(size_t)m * E_ + n];
            float v = acc[nt][r2] + rres;
            acc[nt][r2] = v;
            ssp[r2] += v * v;
        }
    }
#pragma unroll
    for (int off = 1; off < 16; off <<= 1)
#pragma unroll
        for (int r2 = 0; r2 < 4; ++r2)
            ssp[r2] += __shfl_xor(ssp[r2], off);
    if (l15 == 0) {
#pragma unroll
        for (int r2 = 0; r2 < 4; ++r2)
            ss_red[w][g * 4 + r2] = ssp[r2];
    }
    __syncthreads();
#pragma unroll
    for (int r2 = 0; r2 < 4; ++r2) {
        const int lr = g * 4 + r2;
        const float ss = ss_red[mt][lr] + ss_red[2 + mt][lr];
        const float inv = rsqrtf(ss * (1.0f / 192.0f) + 1.1920929e-07f);
        const int m = m0 + mt * 16 + lr;
        size_t orow;
        if (EPI == 2) {        // X -> XR
            const int b = m >> 13, rr = (m >> 3) & 1023, gg = m & 7;
            orow = (((size_t)b * G_ + gg) << 10) + rr;
        } else if (EPI == 3) { // XR -> X
            const int b = m >> 13, gg = (m >> 10) & 7, rr = m & 1023;
            orow = ((((size_t)b << 10) + rr) << 3) + gg;
        } else {
            orow = m;
        }
#pragma unroll
        for (int nt = 0; nt < 6; ++nt) {
            const int n = nh * 96 + nt * 16 + l15;
            const float v = acc[nt][r2] * inv * gvec[n];
            if (EPI == 4) ((float*)Cp)[orow * E_ + n] = v;
            else          ((unsigned short*)Cp)[orow * E_ + n] = f2bf(v);
        }
    }
}

// ---- Fused feature-attention block v5 (R17 best): per-wave-private B slices
// with XOR-swizzled UNPADDED layout; LDS 50.2 KB => 3 blocks/CU; 5 barriers.
template<bool AF32>
__global__ __launch_bounds__(256)
void k_featblock(const void* __restrict__ Xin, const unsigned short* __restrict__ Wqkv,
                 const unsigned short* __restrict__ Wo, const float* __restrict__ gvec,
                 unsigned short* __restrict__ Ynb)
{
    __shared__ __align__(16) unsigned short raw[18688];      // 37376 B (QKVl is max user)
    __shared__ __align__(16) unsigned short AsTl[32][200];   // 12800 B: A (ph1) -> Tl (ph2/3)

    unsigned short (*QKVl)[584] = (unsigned short (*)[584])raw;
    const int m0 = blockIdx.x * 32;
    const int tid = threadIdx.x;
    const int w = tid >> 6, lane = tid & 63, l15 = lane & 15, g = lane >> 4;

    // ---- stage A once (32 x 192, coalesced) ----
#pragma unroll
    for (int j = 0; j < 3; ++j) {
        const int v = tid + 256 * j;          // 0..767
        const int row = v / 24, ch = v % 24;  // 24 chunks of 8 elems per row
        u16x8 aw;
        if (AF32) {
            const float* ap = (const float*)Xin + (size_t)(m0 + row) * E_ + ch * 8;
            float4 x = *(const float4*)ap, y = *(const float4*)(ap + 4);
            aw[0] = f2bf(x.x); aw[1] = f2bf(x.y); aw[2] = f2bf(x.z); aw[3] = f2bf(x.w);
            aw[4] = f2bf(y.x); aw[5] = f2bf(y.y); aw[6] = f2bf(y.z); aw[7] = f2bf(y.w);
        } else {
            aw = *(const u16x8*)((const unsigned short*)Xin + (size_t)(m0 + row) * E_ + ch * 8);
        }
        *(u16x8*)&AsTl[row][ch * 8] = aw;
    }
    __syncthreads();   // B1: A visible to all waves

    // ---- phase 1: QKV = A @ Wqkv^T, per-wave swizzled B slices, no barriers ----
    f32x4 acc[2][9];
#pragma unroll
    for (int mt = 0; mt < 2; ++mt)
#pragma unroll
        for (int nt = 0; nt < 9; ++nt)
#pragma unroll
            for (int r2 = 0; r2 < 4; ++r2) acc[mt][nt][r2] = 0.f;

    unsigned short* slice1 = raw + w * 4608;          // [144][32] swizzled
    u16x8 bv[9];
    auto gload1 = [&](int k0) {
#pragma unroll
        for (int j = 0; j < 9; ++j) {
            const int v = lane + 64 * j;
            bv[j] = *(const u16x8*)(Wqkv + (size_t)(w * 144 + (v >> 2)) * E_ + k0 + ((v & 3) << 3));
        }
    };
    auto swrite1 = [&]() {
#pragma unroll
        for (int j = 0; j < 9; ++j) {
            const int v = lane + 64 * j;
            const int row = v >> 2;
            const int pos = (v & 3) ^ (row & 3);      // XOR swizzle
            *(u16x8*)&slice1[row * 32 + pos * 8] = bv[j];
        }
    };
    const int rb1 = g ^ (l15 & 3);                    // read-side swizzled block

    gload1(0);
    swrite1();
    gload1(32);
#pragma unroll
    for (int kc = 0; kc < 6; ++kc) {
        const int k0 = kc << 5;
        bf16x8 af0 = *(const bf16x8*)&AsTl[l15][k0 + g * 8];
        bf16x8 af1 = *(const bf16x8*)&AsTl[16 + l15][k0 + g * 8];
        bf16x8 bfr[9];
#pragma unroll
        for (int nt = 0; nt < 9; ++nt)
            bfr[nt] = *(const bf16x8*)&slice1[(nt * 16 + l15) * 32 + rb1 * 8];
#pragma unroll
        for (int nt = 0; nt < 9; ++nt) {
            acc[0][nt] = __builtin_amdgcn_mfma_f32_16x16x32_bf16(af0, bfr[nt], acc[0][nt], 0, 0, 0);
            acc[1][nt] = __builtin_amdgcn_mfma_f32_16x16x32_bf16(af1, bfr[nt], acc[1][nt], 0, 0, 0);
        }
        if (kc + 1 < 6) swrite1();                 // bv holds kc+1 (in-order LDS)
        if (kc + 2 < 6) gload1((kc + 2) << 5);
    }
    __syncthreads();   // B2: all waves' Bq reads done before QKVl overlay

    // spill QKV to QKVl (wave w writes its 144-col slice of all 32 rows)
#pragma unroll
    for (int mt = 0; mt < 2; ++mt)
#pragma unroll
        for (int r2 = 0; r2 < 4; ++r2)
#pragma unroll
            for (int nt = 0; nt < 9; ++nt)
                QKVl[mt * 16 + g * 4 + r2][w * 144 + nt * 16 + l15] = f2bf(acc[mt][nt][r2]);

    // prefetch phase-3 chunk-0 weights (latency hides under attn1)
    u16x8 bo[3];
    auto gload3 = [&](int k0) {
#pragma unroll
        for (int j = 0; j < 3; ++j) {
            const int v = lane + 64 * j;
            bo[j] = *(const u16x8*)(Wo + (size_t)(w * 48 + (v >> 2)) * E_ + k0 + ((v & 3) << 3));
        }
    };
    gload3(0);
    __syncthreads();   // B3: QKVl complete

    // ---- phase 2: attn1 (wave w = seq w; lane = i*8+j over G=8) ----
    {
        const int i = lane >> 3, j = lane & 7;
        const int r0 = w * 8;
#pragma unroll
        for (int h = 0; h < 6; ++h) {
            float s = 0.f;
#pragma unroll
            for (int d8 = 0; d8 < 4; ++d8) {
                u16x8 qv = *(const u16x8*)&QKVl[r0 + i][h * 32 + d8 * 8];
                u16x8 kv = *(const u16x8*)&QKVl[r0 + j][192 + h * 32 + d8 * 8];
#pragma unroll
                for (int e = 0; e < 8; ++e) s += bf2f(qv[e]) * bf2f(kv[e]);
            }
            float mx = s;
#pragma unroll
            for (int off = 1; off < 8; off <<= 1) mx = fmaxf(mx, __shfl_xor(mx, off));
            float p = __expf(s - mx);
            float sum = p;
#pragma unroll
            for (int off = 1; off < 8; off <<= 1) sum += __shfl_xor(sum, off);
            p /= sum;
            const int base = lane & ~7;
            float o0 = 0.f, o1 = 0.f, o2 = 0.f, o3 = 0.f;
#pragma unroll
            for (int jj = 0; jj < 8; ++jj) {
                float pj = __shfl(p, base + jj);
                ushort4 vv = *(const ushort4*)&QKVl[r0 + jj][384 + h * 32 + j * 4];
                o0 += pj * bf2f(vv.x); o1 += pj * bf2f(vv.y);
                o2 += pj * bf2f(vv.z); o3 += pj * bf2f(vv.w);
            }
            ushort4 ov; ov.x = f2bf(o0); ov.y = f2bf(o1); ov.z = f2bf(o2); ov.w = f2bf(o3);
            *(ushort4*)&AsTl[r0 + i][h * 32 + j * 4] = ov;   // Tl overlays A
        }
    }

    // preload epilogue residual (hides under phase 3)
    float rv[2][4][3];
#pragma unroll
    for (int mt = 0; mt < 2; ++mt)
#pragma unroll
        for (int r2 = 0; r2 < 4; ++r2) {
            const int m = m0 + mt * 16 + g * 4 + r2;
#pragma unroll
            for (int nt = 0; nt < 3; ++nt) {
                const int n = w * 48 + nt * 16 + l15;
                rv[mt][r2][nt] = AF32 ? ((const float*)Xin)[(size_t)m * E_ + n]
                                      : bf2f(((const unsigned short*)Xin)[(size_t)m * E_ + n]);
            }
        }
    __syncthreads();   // B4: Tl complete; QKVl reads done before Bo overlay

    // ---- phase 3: T @ wo1^T, per-wave swizzled Bo slices, no barriers ----
    unsigned short* slice3 = raw + w * 1536;          // [48][32] swizzled
    f32x4 acc2[2][3];
#pragma unroll
    for (int mt = 0; mt < 2; ++mt)
#pragma unroll
        for (int nt = 0; nt < 3; ++nt)
#pragma unroll
            for (int r2 = 0; r2 < 4; ++r2) acc2[mt][nt][r2] = 0.f;

    auto swrite3 = [&]() {
#pragma unroll
        for (int j = 0; j < 3; ++j) {
            const int v = lane + 64 * j;
            const int row = v >> 2;
            const int pos = (v & 3) ^ (row & 3);
            *(u16x8*)&slice3[row * 32 + pos * 8] = bo[j];
        }
    };
    swrite3();
    gload3(32);
#pragma unroll
    for (int kc = 0; kc < 6; ++kc) {
        const int k0 = kc << 5;
        bf16x8 af0 = *(const bf16x8*)&AsTl[l15][k0 + g * 8];
        bf16x8 af1 = *(const bf16x8*)&AsTl[16 + l15][k0 + g * 8];
        bf16x8 bfr[3];
#pragma unroll
        for (int nt = 0; nt < 3; ++nt)
            bfr[nt] = *(const bf16x8*)&slice3[(nt * 16 + l15) * 32 + rb1 * 8];
#pragma unroll
        for (int nt = 0; nt < 3; ++nt) {
            acc2[0][nt] = __builtin_amdgcn_mfma_f32_16x16x32_bf16(af0, bfr[nt], acc2[0][nt], 0, 0, 0);
            acc2[1][nt] = __builtin_amdgcn_mfma_f32_16x16x32_bf16(af1, bfr[nt], acc2[1][nt], 0, 0, 0);
        }
        if (kc + 1 < 6) swrite3();
        if (kc + 2 < 6) gload3((kc + 2) << 5);
    }

    // ---- epilogue: +res(preloaded), row-RMS*g1, transpose X->XR ----
    float* S = (float*)(raw + 6400);   // beyond Bo slices (elems 0..6143)
    float ssp[2][4] = {};
#pragma unroll
    for (int mt = 0; mt < 2; ++mt)
#pragma unroll
        for (int r2 = 0; r2 < 4; ++r2) {
#pragma unroll
            for (int nt = 0; nt < 3; ++nt) {
                float v = acc2[mt][nt][r2] + rv[mt][r2][nt];
                acc2[mt][nt][r2] = v;
                ssp[mt][r2] += v * v;
            }
        }
#pragma unroll
    for (int off = 1; off < 16; off <<= 1)
#pragma unroll
        for (int mt = 0; mt < 2; ++mt)
#pragma unroll
            for (int r2 = 0; r2 < 4; ++r2)
                ssp[mt][r2] += __shfl_xor(ssp[mt][r2], off);
    if (l15 == 0) {
#pragma unroll
        for (int mt = 0; mt < 2; ++mt)
#pragma unroll
            for (int r2 = 0; r2 < 4; ++r2)
                S[w * 32 + mt * 16 + g * 4 + r2] = ssp[mt][r2];
    }
    __syncthreads();   // B5
#pragma unroll
    for (int mt = 0; mt < 2; ++mt)
#pragma unroll
        for (int r2 = 0; r2 < 4; ++r2) {
            const int row = mt * 16 + g * 4 + r2;
            const float ss = S[row] + S[32 + row] + S[64 + row] + S[96 + row];
            const float inv = rsqrtf(ss * (1.0f / 192.0f) + 1.1920929e-07f);
            const int m = m0 + row;
            const int b = m >> 13, rr = (m >> 3) & 1023, gg = m & 7;
            const size_t orow = (((size_t)(b * G_ + gg)) << 10) + rr;
#pragma unroll
            for (int nt = 0; nt < 3; ++nt) {
                const int n = w * 48 + nt * 16 + l15;
                Ynb[orow * E_ + n] = f2bf(acc2[mt][nt][r2] * inv * gvec[n]);
            }
        }
}

// ---- Row attention v7: 8 waves x 16 q = 128 q-rows per block (512 threads).
// Same per-wave serial structure as the proven 64-q form (16 q/wave,
// register-P, tr-read V, ones-row denominator, exp2 domain, no max-tracking),
// but the staged K/V chunk serves 2x the q-rows and staging roles are split:
// tid<256 stages K, tid>=256 stages V (1 load + 1 LDS write per thread per
// chunk, half the staging chain). Grid 1536; 4 blocks/CU = 32 waves (cap).
__global__ __launch_bounds__(512)
void k_attn2(const unsigned short* __restrict__ QKV, unsigned short* __restrict__ T,
             const int* __restrict__ sep_ptr)
{
    __shared__ __align__(16) unsigned short K_lds[64][40];
    __shared__ __align__(16) unsigned short V_lds[2048];   // [dg(2)][kblk(16)][4][16]

    const int sep = *sep_ptr;
    const int bid = blockIdx.x;
    const int sh = ((bid >> 6) << 3) | (bid & 7);   // same (s,h) => same XCD
    const int qtile = (bid >> 3) & 7;
    const int s = sh / H_, h = sh % H_;
    const int q0 = qtile * 128;

    const int tid = threadIdx.x;
    const int w = tid >> 6;                          // 0..7
    const int lane = tid & 63;
    const int l15 = lane & 15;
    const int g = lane >> 4;

    const int qrow = q0 + w * 16 + l15;
    u16x8 qf = *(const u16x8*)(QKV + ((size_t)s * R_ + qrow) * 576 + h * D_ + g * 8);

    u16x8 onesu;
#pragma unroll
    for (int e = 0; e < 8; ++e) onesu[e] = 0x3F80;  // bf16 1.0
    const bf16x8 onesf = (bf16x8)onesu;

    const bool lo = (q0 < sep);
    const bool hi = (q0 + 128 > sep);
    const int npass = (lo && hi) ? 2 : 1;
    const int nChunk = (sep + 63) >> 6;

    // staging: threads 0-255 own K, threads 256-511 own V (one u16x8 each)
    const int st = tid & 255;
    const int skey = st >> 2;
    const int sg   = st & 3;
    const bool stK = (tid < 256);
    const int vst = ((sg >> 1) * 16 + (skey >> 2)) * 64 + (skey & 3) * 16 + (sg & 1) * 8;
    const unsigned vaddr = (unsigned)(size_t)&V_lds[0] + (unsigned)(g * 128 + l15 * 2);

    for (int pass = 0; pass < npass; ++pass) {
        const int hk = (pass == 0) ? (lo ? h : 0) : 0;
        const unsigned short* Kb = QKV + (size_t)s * R_ * 576 + 192 + hk * D_;
        const unsigned short* Vb = QKV + (size_t)s * R_ * 576 + 384 + hk * D_;
        const unsigned short* Sb = stK ? Kb : Vb;

        f32x4 o0 = {0.f, 0.f, 0.f, 0.f};
        f32x4 o1 = {0.f, 0.f, 0.f, 0.f};
        f32x4 o2 = {0.f, 0.f, 0.f, 0.f};   // ones-row: running sum of P

        u16x8 kv = *(const u16x8*)(Sb + (size_t)skey * 576 + sg * 8);

        for (int kc = 0; kc < nChunk; ++kc) {
            const int kbase = kc * 64;
            const bool full = (kbase + 64 <= sep);
            __syncthreads();
            if (stK) *(u16x8*)&K_lds[skey][sg * 8] = kv;
            else     *(u16x8*)&V_lds[vst] = kv;
            __syncthreads();
            if (kc + 1 < nChunk)
                kv = *(const u16x8*)(Sb + (size_t)(kbase + 64 + skey) * 576 + sg * 8);

            f32x4 sc[4];
            const f32x4 zf = {0.f, 0.f, 0.f, 0.f};
            __builtin_amdgcn_s_setprio(1);
#pragma unroll
            for (int t = 0; t < 4; ++t) {
                bf16x8 a = *(const bf16x8*)&K_lds[t * 16 + l15][g * 8];
                sc[t] = __builtin_amdgcn_mfma_f32_16x16x32_bf16(a, (bf16x8)qf, zf, 0, 0, 0);
            }
            __builtin_amdgcn_s_setprio(0);
            if (!full) {
#pragma unroll
                for (int t = 0; t < 4; ++t)
#pragma unroll
                    for (int r = 0; r < 4; ++r)
                        if (kbase + t * 16 + g * 4 + r >= sep) sc[t][r] = -1e30f;
            }
            // P = exp2(s) directly (implicit max = 0); pack to B-fragments.
            bf16x8 pb0, pb1;
            {
                u16x8 p0, p1;
#pragma unroll
                for (int r = 0; r < 4; ++r) {
                    p0[r]     = f2bf(exp2f(sc[0][r]));
                    p0[4 + r] = f2bf(exp2f(sc[1][r]));
                    p1[r]     = f2bf(exp2f(sc[2][r]));
                    p1[4 + r] = f2bf(exp2f(sc[3][r]));
                }
                pb0 = (bf16x8)p0; pb1 = (bf16x8)p1;
            }
            unsigned long long t0, t1, t2, t3, t4, t5, t6, t7;
            asm volatile(
                "ds_read_b64_tr_b16 %0, %8 offset:0\n\t"
                "ds_read_b64_tr_b16 %1, %8 offset:512\n\t"
                "ds_read_b64_tr_b16 %2, %8 offset:1024\n\t"
                "ds_read_b64_tr_b16 %3, %8 offset:1536\n\t"
                "ds_read_b64_tr_b16 %4, %8 offset:2048\n\t"
                "ds_read_b64_tr_b16 %5, %8 offset:2560\n\t"
                "ds_read_b64_tr_b16 %6, %8 offset:3072\n\t"
                "ds_read_b64_tr_b16 %7, %8 offset:3584\n\t"
                "s_waitcnt lgkmcnt(0)"
                : "=&v"(t0), "=&v"(t1), "=&v"(t2), "=&v"(t3),
                  "=&v"(t4), "=&v"(t5), "=&v"(t6), "=&v"(t7)
                : "v"(vaddr)
                : "memory");
            __builtin_amdgcn_sched_barrier(0);
            __builtin_amdgcn_s_setprio(1);
            o0 = __builtin_amdgcn_mfma_f32_16x16x32_bf16(mk8(t0, t1), pb0, o0, 0, 0, 0);
            o1 = __builtin_amdgcn_mfma_f32_16x16x32_bf16(mk8(t4, t5), pb0, o1, 0, 0, 0);
            o2 = __builtin_amdgcn_mfma_f32_16x16x32_bf16(onesf,       pb0, o2, 0, 0, 0);
            o0 = __builtin_amdgcn_mfma_f32_16x16x32_bf16(mk8(t2, t3), pb1, o0, 0, 0, 0);
            o1 = __builtin_amdgcn_mfma_f32_16x16x32_bf16(mk8(t6, t7), pb1, o1, 0, 0, 0);
            o2 = __builtin_amdgcn_mfma_f32_16x16x32_bf16(onesf,       pb1, o2, 0, 0, 0);
            __builtin_amdgcn_s_setprio(0);
        }

        const bool valid = (npass == 1) || (pass == 0 ? (qrow < sep) : (qrow >= sep));
        if (valid) {
            const float inv = 1.f / o2[0];
            unsigned short* tp = T + ((size_t)s * R_ + qrow) * E_ + h * D_;
            ushort4 v0, v1;
            v0.x = f2bf(o0[0] * inv); v0.y = f2bf(o0[1] * inv);
            v0.z = f2bf(o0[2] * inv); v0.w = f2bf(o0[3] * inv);
            v1.x = f2bf(o1[0] * inv); v1.y = f2bf(o1[1] * inv);
            v1.z = f2bf(o1[2] * inv); v1.w = f2bf(o1[3] * inv);
            *(ushort4*)(tp + g * 4)      = v0;
            *(ushort4*)(tp + 16 + g * 4) = v1;
        }
    }
}

extern "C" void kernel_launch(void* const* d_in, const int* in_sizes, int n_in,
                              void* d_out, int out_size, void* d_ws, size_t ws_size,
                              hipStream_t stream) {
    const float* hidden = (const float*)d_in[0];
    const float* Wq1 = (const float*)d_in[1];
    const float* Wk1 = (const float*)d_in[2];
    const float* Wv1 = (const float*)d_in[3];
    const float* Wo1 = (const float*)d_in[4];
    const float* Wq2 = (const float*)d_in[5];
    const float* Wk2 = (const float*)d_in[6];
    const float* Wv2 = (const float*)d_in[7];
    const float* Wo2 = (const float*)d_in[8];
    const float* W1  = (const float*)d_in[9];
    const float* W2  = (const float*)d_in[10];
    const float* g1  = (const float*)d_in[11];
    const float* g2  = (const float*)d_in[12];
    const float* g3  = (const float*)d_in[13];
    const int*   sep = (const int*)d_in[14];

    float* Xout = (float*)d_out;                    // final f32 X-layout output
    unsigned short* ws = (unsigned short*)d_ws;
    unsigned short* QKVb = ws;                      // [M][576] bf16 (aliases H1 [M][384])
    unsigned short* Tb   = QKVb + (size_t)M_ * 576;
    unsigned short* Ynb  = Tb + NBUF;               // rms-g1 output, XR layout
    unsigned short* Xcb  = Ynb + NBUF;              // rms-g2 output, X layout
    unsigned short* Xb   = Xcb + NBUF;              // inter-layer residual (layers 0-2)
    unsigned short* Wt   = Xb + NBUF;
    unsigned short* H1b  = QKVb;

    const dim3 blk(256);
    const dim3 blk512(512);
    const dim3 gQKV(M_ / 64, 3);
    const dim3 gW1(M_ / 64, 2);
    const dim3 g32(M_ / 32);                        // 1024 blocks
    const dim3 gA2(32 * H_ * 8);                    // (s,h) x 8 q-tiles of 128 rows

    k_convw_all<<<dim3(432 * L_), blk, 0, stream>>>(Wq1, Wk1, Wv1, Wo1, Wq2, Wk2, Wv2, Wo2, W1, W2, Wt);

    for (int i = 0; i < L_; ++i) {
        unsigned short* wl = Wt + (size_t)i * WPL;
        const unsigned short* wqkv1 = wl;
        const unsigned short* wo1   = wl + 3 * (size_t)E_ * E_;
        const unsigned short* wqkv2 = wl + 4 * (size_t)E_ * E_;
        const unsigned short* wo2   = wl + 7 * (size_t)E_ * E_;
        const unsigned short* w1    = wl + 8 * (size_t)E_ * E_;
        const unsigned short* w2    = wl + 8 * (size_t)E_ * E_ + (size_t)E_ * F_;
        const float* g1i = g1 + (size_t)i * E_;
        const float* g2i = g2 + (size_t)i * E_;
        const float* g3i = g3 + (size_t)i * E_;

        // --- fused feature-attention block: X/hidden -> Ynb (XR) ---
        if (i == 0)
            k_featblock<true><<<g32, blk, 0, stream>>>(hidden, wqkv1, wo1, g1i, Ynb);
        else
            k_featblock<false><<<g32, blk, 0, stream>>>(Xb, wqkv1, wo1, g1i, Ynb);
        // --- row attention block ---
        k_gemm_mfma<true, 0><<<gQKV, blk, 0, stream>>>(Ynb, wqkv2, QKVb, 576, E_);
        k_attn2<<<gA2, blk512, 0, stream>>>(QKVb, Tb, sep);
        k_gemm_rms32<true, 3><<<g32, blk, 0, stream>>>(Tb, wo2, Ynb, g2i, Xcb, E_);
        // --- MLP block ---
        k_gemm_mfma<true, 1><<<gW1, blk, 0, stream>>>(Xcb, w1, H1b, F_, E_);
        if (i == L_ - 1)
            k_gemm_rms32<true, 4><<<g32, blk, 0, stream>>>(H1b, w2, Xcb, g3i, Xout, F_);
        else
            k_gemm_rms32<true, 5><<<g32, blk, 0, stream>>>(H1b, w2, Xcb, g3i, Xb, F_);
    }
}

// Round 21
// 573.231 us; speedup vs baseline: 1.0900x; 1.0229x over previous
//
#include <hip/hip_runtime.h>
#include <hip/hip_bf16.h>
#include <math.h>

#define B_ 4
#define R_ 1024
#define G_ 8
#define E_ 192
#define H_ 6
#define D_ 32
#define L_ 4
#define F_ 384
#define M_ (B_*R_*G_)              // 32768 rows
static const size_t NBUF = (size_t)M_ * E_;       // 6291456 elems
static const size_t WPL  = 8 * (size_t)E_ * E_ + 2 * (size_t)E_ * F_;  // bf16/layer

typedef __attribute__((ext_vector_type(8))) short bf16x8;
typedef __attribute__((ext_vector_type(8))) unsigned short u16x8;
typedef __attribute__((ext_vector_type(4))) float f32x4;

__device__ __forceinline__ float gelu_exact(float x) {
    return 0.5f * x * (1.0f + erff(x * 0.7071067811865475f));
}
__device__ __forceinline__ unsigned short f2bf(float f) {
    __hip_bfloat16 h = __float2bfloat16(f);
    return *(unsigned short*)&h;
}
__device__ __forceinline__ float bf2f(unsigned short h) {
    union { unsigned u; float f; } v; v.u = ((unsigned)h) << 16; return v.f;
}
__device__ __forceinline__ bf16x8 mk8(unsigned long long lo, unsigned long long hi) {
    union { unsigned long long q[2]; bf16x8 v; } u;
    u.q[0] = lo; u.q[1] = hi; return u.v;
}

// ---- one-shot: transpose+convert all weights to Wt[N][K] bf16.
// Scale folds: Wq1 *= 1/sqrt(D); Wq2 *= log2(e)/sqrt(D)  (attn2 runs in exp2 domain).
__global__ __launch_bounds__(256)
void k_convw_all(const float* __restrict__ Wq1, const float* __restrict__ Wk1,
                 const float* __restrict__ Wv1, const float* __restrict__ Wo1,
                 const float* __restrict__ Wq2, const float* __restrict__ Wk2,
                 const float* __restrict__ Wv2, const float* __restrict__ Wo2,
                 const float* __restrict__ W1,  const float* __restrict__ W2,
                 unsigned short* __restrict__ Wt)
{
    const int t = blockIdx.x;
    const int layer = t / 432;
    const int r = t % 432;
    const float* src; unsigned short* dst; int K, N; float scale = 1.f; int tile;
    if (r < 288) {
        const int w = r / 36; tile = r % 36; K = E_; N = E_;
        const float* tab[8] = {Wq1, Wk1, Wv1, Wo1, Wq2, Wk2, Wv2, Wo2};
        src = tab[w] + (size_t)layer * E_ * E_;
        dst = Wt + (size_t)layer * WPL + (size_t)w * E_ * E_;
        if (w == 0) scale = 0.17677669529663687f;                       // 1/sqrt(32)
        if (w == 4) scale = 0.17677669529663687f * 1.4426950408889634f; // log2e/sqrt(32)
    } else if (r < 360) {
        tile = r - 288; K = E_; N = F_;
        src = W1 + (size_t)layer * E_ * F_;
        dst = Wt + (size_t)layer * WPL + 8 * (size_t)E_ * E_;
    } else {
        tile = r - 360; K = F_; N = E_;
        src = W2 + (size_t)layer * E_ * F_;
        dst = Wt + (size_t)layer * WPL + 8 * (size_t)E_ * E_ + (size_t)E_ * F_;
    }
    const int ntx = N / 32;
    const int kb = (tile / ntx) * 32, nb = (tile % ntx) * 32;
    __shared__ float tl[32][33];
    const int tx = threadIdx.x & 31, ty = threadIdx.x >> 5;
    for (int i2 = 0; i2 < 32; i2 += 8)
        tl[ty + i2][tx] = src[(size_t)(kb + ty + i2) * N + nb + tx];
    __syncthreads();
    for (int i2 = 0; i2 < 32; i2 += 8)
        dst[(size_t)(nb + ty + i2) * K + kb + tx] = f2bf(tl[tx][ty + i2] * scale);
}

// ---- MFMA GEMM, tile 64 x 192, BK=32, 4 waves, reg-prefetch pipeline (R8 form).
// EPI: 0 = store bf16 at [m][n0+n], ldc; 1 = gelu -> bf16, ldc.
template<bool ABF16, int EPI>
__global__ __launch_bounds__(256)
void k_gemm_mfma(const void* __restrict__ Ap, const unsigned short* __restrict__ Wt,
                 void* __restrict__ Cp, int ldc, int K)
{
    __shared__ unsigned short As[64][40];
    __shared__ unsigned short Bs[192][40];
    const int m0 = blockIdx.x * 64;
    const int n0 = blockIdx.y * 192;
    const int tid = threadIdx.x;
    const int w = tid >> 6, lane = tid & 63, l15 = lane & 15, g = lane >> 4;
    const int arow = tid >> 2, akoff = (tid & 3) << 3;
    f32x4 acc[4][3];
#pragma unroll
    for (int mt = 0; mt < 4; ++mt)
#pragma unroll
        for (int nt = 0; nt < 3; ++nt)
#pragma unroll
            for (int r2 = 0; r2 < 4; ++r2) acc[mt][nt][r2] = 0.f;
    const int nK = K >> 5;

    float4 ax, ay; u16x8 av; u16x8 bv0, bv1, bv2;
    auto gload = [&](int k0) {
        if (ABF16) {
            av = *(const u16x8*)((const unsigned short*)Ap + (size_t)(m0 + arow) * K + k0 + akoff);
        } else {
            const float* ap = (const float*)Ap + (size_t)(m0 + arow) * K + k0 + akoff;
            ax = *(const float4*)ap; ay = *(const float4*)(ap + 4);
        }
        bv0 = *(const u16x8*)(Wt + (size_t)(n0 + arow      ) * K + k0 + akoff);
        bv1 = *(const u16x8*)(Wt + (size_t)(n0 + arow +  64) * K + k0 + akoff);
        bv2 = *(const u16x8*)(Wt + (size_t)(n0 + arow + 128) * K + k0 + akoff);
    };
    auto swrite = [&]() {
        u16x8 aw;
        if (ABF16) aw = av;
        else {
            aw[0] = f2bf(ax.x); aw[1] = f2bf(ax.y); aw[2] = f2bf(ax.z); aw[3] = f2bf(ax.w);
            aw[4] = f2bf(ay.x); aw[5] = f2bf(ay.y); aw[6] = f2bf(ay.z); aw[7] = f2bf(ay.w);
        }
        *(u16x8*)&As[arow][akoff] = aw;
        *(u16x8*)&Bs[arow][akoff] = bv0;
        *(u16x8*)&Bs[arow + 64][akoff] = bv1;
        *(u16x8*)&Bs[arow + 128][akoff] = bv2;
    };

    gload(0);
    for (int kc = 0; kc < nK; ++kc) {
        __syncthreads();
        swrite();
        __syncthreads();
        if (kc + 1 < nK) gload((kc + 1) << 5);
        bf16x8 af[4], bfr[3];
#pragma unroll
        for (int mt = 0; mt < 4; ++mt) af[mt] = *(const bf16x8*)&As[mt * 16 + l15][g * 8];
#pragma unroll
        for (int nt = 0; nt < 3; ++nt) bfr[nt] = *(const bf16x8*)&Bs[w * 48 + nt * 16 + l15][g * 8];
#pragma unroll
        for (int mt = 0; mt < 4; ++mt)
#pragma unroll
            for (int nt = 0; nt < 3; ++nt)
                acc[mt][nt] = __builtin_amdgcn_mfma_f32_16x16x32_bf16(af[mt], bfr[nt], acc[mt][nt], 0, 0, 0);
    }

#pragma unroll
    for (int mt = 0; mt < 4; ++mt)
#pragma unroll
        for (int r2 = 0; r2 < 4; ++r2) {
            const int m = m0 + mt * 16 + g * 4 + r2;
#pragma unroll
            for (int nt = 0; nt < 3; ++nt) {
                const int n = w * 48 + nt * 16 + l15;
                float v = acc[mt][nt][r2];
                if (EPI == 1) v = gelu_exact(v);
                ((unsigned short*)Cp)[(size_t)m * ldc + n0 + n] = f2bf(v);
            }
        }
}

// ---- MFMA GEMM + residual + row-RMSNorm v2: tile 64 x 192, 8 waves (512 thr),
// grid M/64 = 512. Per-wave work identical to the 4-wave form (one m-tile x
// 6 n-tiles); B panel staged once per 64 rows (was twice); staging split:
// tid>=256 stage A, all stage B rows 0-127, tid<256 stage B rows 128-191.
// EPI: 3 = ->bf16, transpose XR->X; 4 = ->f32; 5 = ->bf16.
template<bool RESBF16, int EPI>
__global__ __launch_bounds__(512)
void k_gemm_rms64(const unsigned short* __restrict__ Ap, const unsigned short* __restrict__ Wt,
                  const void* __restrict__ Resp, const float* __restrict__ gvec,
                  void* __restrict__ Cp, int K)
{
    __shared__ unsigned short As[64][40];
    __shared__ unsigned short Bs[192][40];
    __shared__ float ss_red[8][16];
    const int m0 = blockIdx.x * 64;
    const int tid = threadIdx.x;
    const int w = tid >> 6, lane = tid & 63, l15 = lane & 15, g = lane >> 4;
    const int mt = w & 3, nh = w >> 2;
    const int st = tid & 255;
    const int arow = st >> 2, akoff = (st & 3) << 3;          // A: tid>=256
    const int b0row = tid >> 2, b0off = (tid & 3) << 3;       // B rows 0..127: all
    const int b1row = 128 + (st >> 2), b1off = (st & 3) << 3; // B rows 128..191: tid<256
    f32x4 acc[6];
#pragma unroll
    for (int nt = 0; nt < 6; ++nt)
#pragma unroll
        for (int r2 = 0; r2 < 4; ++r2) acc[nt][r2] = 0.f;
    const int nK = K >> 5;

    u16x8 av, bv0, bv1;
    auto gload = [&](int k0) {
        if (tid >= 256)
            av = *(const u16x8*)(Ap + (size_t)(m0 + arow) * K + k0 + akoff);
        bv0 = *(const u16x8*)(Wt + (size_t)b0row * K + k0 + b0off);
        if (tid < 256)
            bv1 = *(const u16x8*)(Wt + (size_t)b1row * K + k0 + b1off);
    };
    auto swrite = [&]() {
        if (tid >= 256) *(u16x8*)&As[arow][akoff] = av;
        *(u16x8*)&Bs[b0row][b0off] = bv0;
        if (tid < 256) *(u16x8*)&Bs[b1row][b1off] = bv1;
    };

    gload(0);
    for (int kc = 0; kc < nK; ++kc) {
        __syncthreads();
        swrite();
        __syncthreads();
        if (kc + 1 < nK) gload((kc + 1) << 5);
        bf16x8 af = *(const bf16x8*)&As[mt * 16 + l15][g * 8];
        bf16x8 bfr[6];
#pragma unroll
        for (int nt = 0; nt < 6; ++nt) bfr[nt] = *(const bf16x8*)&Bs[nh * 96 + nt * 16 + l15][g * 8];
#pragma unroll
        for (int nt = 0; nt < 6; ++nt)
            acc[nt] = __builtin_amdgcn_mfma_f32_16x16x32_bf16(af, bfr[nt], acc[nt], 0, 0, 0);
    }

    float ssp[4] = {0.f, 0.f, 0.f, 0.f};
#pragma unroll
    for (int r2 = 0; r2 < 4; ++r2) {
        const int m = m0 + mt * 16 + g * 4 + r2;
#pragma unroll
        for (int nt = 0; nt < 6; ++nt) {
            const int n = nh * 96 + nt * 16 + l15;
            float rres = RESBF16 ? bf2f(((const unsigned short*)Resp)[(size_t)m * E_ + n])
                                 : ((const float*)Resp)[(size_t)m * E_ + n];
            float v = acc[nt][r2] + rres;
            acc[nt][r2] = v;
            ssp[r2] += v * v;
        }
    }
#pragma unroll
    for (int off = 1; off < 16; off <<= 1)
#pragma unroll
        for (int r2 = 0; r2 < 4; ++r2)
            ssp[r2] += __shfl_xor(ssp[r2], off);
    if (l15 == 0) {
#pragma unroll
        for (int r2 = 0; r2 < 4; ++r2)
            ss_red[w][g * 4 + r2] = ssp[r2];
    }
    __syncthreads();
#pragma unroll
    for (int r2 = 0; r2 < 4; ++r2) {
        const int lr = g * 4 + r2;
        const float ss = ss_red[mt][lr] + ss_red[4 + mt][lr];
        const float inv = rsqrtf(ss * (1.0f / 192.0f) + 1.1920929e-07f);
        const int m = m0 + mt * 16 + lr;
        size_t orow;
        if (EPI == 3) {        // XR -> X
            const int b = m >> 13, gg = (m >> 10) & 7, rr = m & 1023;
            orow = ((((size_t)b << 10) + rr) << 3) + gg;
        } else {
            orow = m;
        }
#pragma unroll
        for (int nt = 0; nt < 6; ++nt) {
            const int n = nh * 96 + nt * 16 + l15;
            const float v = acc[nt][r2] * inv * gvec[n];
            if (EPI == 4) ((float*)Cp)[orow * E_ + n] = v;
            else          ((unsigned short*)Cp)[orow * E_ + n] = f2bf(v);
        }
    }
}

// ---- Fused feature-attention block v5 (R17 best): per-wave-private B slices
// with XOR-swizzled UNPADDED layout; LDS 50.2 KB => 3 blocks/CU; 5 barriers.
template<bool AF32>
__global__ __launch_bounds__(256)
void k_featblock(const void* __restrict__ Xin, const unsigned short* __restrict__ Wqkv,
                 const unsigned short* __restrict__ Wo, const float* __restrict__ gvec,
                 unsigned short* __restrict__ Ynb)
{
    __shared__ __align__(16) unsigned short raw[18688];      // 37376 B (QKVl is max user)
    __shared__ __align__(16) unsigned short AsTl[32][200];   // 12800 B: A (ph1) -> Tl (ph2/3)

    unsigned short (*QKVl)[584] = (unsigned short (*)[584])raw;
    const int m0 = blockIdx.x * 32;
    const int tid = threadIdx.x;
    const int w = tid >> 6, lane = tid & 63, l15 = lane & 15, g = lane >> 4;

    // ---- stage A once (32 x 192, coalesced) ----
#pragma unroll
    for (int j = 0; j < 3; ++j) {
        const int v = tid + 256 * j;          // 0..767
        const int row = v / 24, ch = v % 24;  // 24 chunks of 8 elems per row
        u16x8 aw;
        if (AF32) {
            const float* ap = (const float*)Xin + (size_t)(m0 + row) * E_ + ch * 8;
            float4 x = *(const float4*)ap, y = *(const float4*)(ap + 4);
            aw[0] = f2bf(x.x); aw[1] = f2bf(x.y); aw[2] = f2bf(x.z); aw[3] = f2bf(x.w);
            aw[4] = f2bf(y.x); aw[5] = f2bf(y.y); aw[6] = f2bf(y.z); aw[7] = f2bf(y.w);
        } else {
            aw = *(const u16x8*)((const unsigned short*)Xin + (size_t)(m0 + row) * E_ + ch * 8);
        }
        *(u16x8*)&AsTl[row][ch * 8] = aw;
    }
    __syncthreads();   // B1: A visible to all waves

    // ---- phase 1: QKV = A @ Wqkv^T, per-wave swizzled B slices, no barriers ----
    f32x4 acc[2][9];
#pragma unroll
    for (int mt = 0; mt < 2; ++mt)
#pragma unroll
        for (int nt = 0; nt < 9; ++nt)
#pragma unroll
            for (int r2 = 0; r2 < 4; ++r2) acc[mt][nt][r2] = 0.f;

    unsigned short* slice1 = raw + w * 4608;          // [144][32] swizzled
    u16x8 bv[9];
    auto gload1 = [&](int k0) {
#pragma unroll
        for (int j = 0; j < 9; ++j) {
            const int v = lane + 64 * j;
            bv[j] = *(const u16x8*)(Wqkv + (size_t)(w * 144 + (v >> 2)) * E_ + k0 + ((v & 3) << 3));
        }
    };
    auto swrite1 = [&]() {
#pragma unroll
        for (int j = 0; j < 9; ++j) {
            const int v = lane + 64 * j;
            const int row = v >> 2;
            const int pos = (v & 3) ^ (row & 3);      // XOR swizzle
            *(u16x8*)&slice1[row * 32 + pos * 8] = bv[j];
        }
    };
    const int rb1 = g ^ (l15 & 3);                    // read-side swizzled block

    gload1(0);
    swrite1();
    gload1(32);
#pragma unroll
    for (int kc = 0; kc < 6; ++kc) {
        const int k0 = kc << 5;
        bf16x8 af0 = *(const bf16x8*)&AsTl[l15][k0 + g * 8];
        bf16x8 af1 = *(const bf16x8*)&AsTl[16 + l15][k0 + g * 8];
        bf16x8 bfr[9];
#pragma unroll
        for (int nt = 0; nt < 9; ++nt)
            bfr[nt] = *(const bf16x8*)&slice1[(nt * 16 + l15) * 32 + rb1 * 8];
#pragma unroll
        for (int nt = 0; nt < 9; ++nt) {
            acc[0][nt] = __builtin_amdgcn_mfma_f32_16x16x32_bf16(af0, bfr[nt], acc[0][nt], 0, 0, 0);
            acc[1][nt] = __builtin_amdgcn_mfma_f32_16x16x32_bf16(af1, bfr[nt], acc[1][nt], 0, 0, 0);
        }
        if (kc + 1 < 6) swrite1();                 // bv holds kc+1 (in-order LDS)
        if (kc + 2 < 6) gload1((kc + 2) << 5);
    }
    __syncthreads();   // B2: all waves' Bq reads done before QKVl overlay

    // spill QKV to QKVl (wave w writes its 144-col slice of all 32 rows)
#pragma unroll
    for (int mt = 0; mt < 2; ++mt)
#pragma unroll
        for (int r2 = 0; r2 < 4; ++r2)
#pragma unroll
            for (int nt = 0; nt < 9; ++nt)
                QKVl[mt * 16 + g * 4 + r2][w * 144 + nt * 16 + l15] = f2bf(acc[mt][nt][r2]);

    // prefetch phase-3 chunk-0 weights (latency hides under attn1)
    u16x8 bo[3];
    auto gload3 = [&](int k0) {
#pragma unroll
        for (int j = 0; j < 3; ++j) {
            const int v = lane + 64 * j;
            bo[j] = *(const u16x8*)(Wo + (size_t)(w * 48 + (v >> 2)) * E_ + k0 + ((v & 3) << 3));
        }
    };
    gload3(0);
    __syncthreads();   // B3: QKVl complete

    // ---- phase 2: attn1 (wave w = seq w; lane = i*8+j over G=8) ----
    {
        const int i = lane >> 3, j = lane & 7;
        const int r0 = w * 8;
#pragma unroll
        for (int h = 0; h < 6; ++h) {
            float s = 0.f;
#pragma unroll
            for (int d8 = 0; d8 < 4; ++d8) {
                u16x8 qv = *(const u16x8*)&QKVl[r0 + i][h * 32 + d8 * 8];
                u16x8 kv = *(const u16x8*)&QKVl[r0 + j][192 + h * 32 + d8 * 8];
#pragma unroll
                for (int e = 0; e < 8; ++e) s += bf2f(qv[e]) * bf2f(kv[e]);
            }
            float mx = s;
#pragma unroll
            for (int off = 1; off < 8; off <<= 1) mx = fmaxf(mx, __shfl_xor(mx, off));
            float p = __expf(s - mx);
            float sum = p;
#pragma unroll
            for (int off = 1; off < 8; off <<= 1) sum += __shfl_xor(sum, off);
            p /= sum;
            const int base = lane & ~7;
            float o0 = 0.f, o1 = 0.f, o2 = 0.f, o3 = 0.f;
#pragma unroll
            for (int jj = 0; jj < 8; ++jj) {
                float pj = __shfl(p, base + jj);
                ushort4 vv = *(const ushort4*)&QKVl[r0 + jj][384 + h * 32 + j * 4];
                o0 += pj * bf2f(vv.x); o1 += pj * bf2f(vv.y);
                o2 += pj * bf2f(vv.z); o3 += pj * bf2f(vv.w);
            }
            ushort4 ov; ov.x = f2bf(o0); ov.y = f2bf(o1); ov.z = f2bf(o2); ov.w = f2bf(o3);
            *(ushort4*)&AsTl[r0 + i][h * 32 + j * 4] = ov;   // Tl overlays A
        }
    }

    // preload epilogue residual (hides under phase 3)
    float rv[2][4][3];
#pragma unroll
    for (int mt = 0; mt < 2; ++mt)
#pragma unroll
        for (int r2 = 0; r2 < 4; ++r2) {
            const int m = m0 + mt * 16 + g * 4 + r2;
#pragma unroll
            for (int nt = 0; nt < 3; ++nt) {
                const int n = w * 48 + nt * 16 + l15;
                rv[mt][r2][nt] = AF32 ? ((const float*)Xin)[(size_t)m * E_ + n]
                                      : bf2f(((const unsigned short*)Xin)[(size_t)m * E_ + n]);
            }
        }
    __syncthreads();   // B4: Tl complete; QKVl reads done before Bo overlay

    // ---- phase 3: T @ wo1^T, per-wave swizzled Bo slices, no barriers ----
    unsigned short* slice3 = raw + w * 1536;          // [48][32] swizzled
    f32x4 acc2[2][3];
#pragma unroll
    for (int mt = 0; mt < 2; ++mt)
#pragma unroll
        for (int nt = 0; nt < 3; ++nt)
#pragma unroll
            for (int r2 = 0; r2 < 4; ++r2) acc2[mt][nt][r2] = 0.f;

    auto swrite3 = [&]() {
#pragma unroll
        for (int j = 0; j < 3; ++j) {
            const int v = lane + 64 * j;
            const int row = v >> 2;
            const int pos = (v & 3) ^ (row & 3);
            *(u16x8*)&slice3[row * 32 + pos * 8] = bo[j];
        }
    };
    swrite3();
    gload3(32);
#pragma unroll
    for (int kc = 0; kc < 6; ++kc) {
        const int k0 = kc << 5;
        bf16x8 af0 = *(const bf16x8*)&AsTl[l15][k0 + g * 8];
        bf16x8 af1 = *(const bf16x8*)&AsTl[16 + l15][k0 + g * 8];
        bf16x8 bfr[3];
#pragma unroll
        for (int nt = 0; nt < 3; ++nt)
            bfr[nt] = *(const bf16x8*)&slice3[(nt * 16 + l15) * 32 + rb1 * 8];
#pragma unroll
        for (int nt = 0; nt < 3; ++nt) {
            acc2[0][nt] = __builtin_amdgcn_mfma_f32_16x16x32_bf16(af0, bfr[nt], acc2[0][nt], 0, 0, 0);
            acc2[1][nt] = __builtin_amdgcn_mfma_f32_16x16x32_bf16(af1, bfr[nt], acc2[1][nt], 0, 0, 0);
        }
        if (kc + 1 < 6) swrite3();
        if (kc + 2 < 6) gload3((kc + 2) << 5);
    }

    // ---- epilogue: +res(preloaded), row-RMS*g1, transpose X->XR ----
    float* S = (float*)(raw + 6400);   // beyond Bo slices (elems 0..6143)
    float ssp[2][4] = {};
#pragma unroll
    for (int mt = 0; mt < 2; ++mt)
#pragma unroll
        for (int r2 = 0; r2 < 4; ++r2) {
#pragma unroll
            for (int nt = 0; nt < 3; ++nt) {
                float v = acc2[mt][nt][r2] + rv[mt][r2][nt];
                acc2[mt][nt][r2] = v;
                ssp[mt][r2] += v * v;
            }
        }
#pragma unroll
    for (int off = 1; off < 16; off <<= 1)
#pragma unroll
        for (int mt = 0; mt < 2; ++mt)
#pragma unroll
            for (int r2 = 0; r2 < 4; ++r2)
                ssp[mt][r2] += __shfl_xor(ssp[mt][r2], off);
    if (l15 == 0) {
#pragma unroll
        for (int mt = 0; mt < 2; ++mt)
#pragma unroll
            for (int r2 = 0; r2 < 4; ++r2)
                S[w * 32 + mt * 16 + g * 4 + r2] = ssp[mt][r2];
    }
    __syncthreads();   // B5
#pragma unroll
    for (int mt = 0; mt < 2; ++mt)
#pragma unroll
        for (int r2 = 0; r2 < 4; ++r2) {
            const int row = mt * 16 + g * 4 + r2;
            const float ss = S[row] + S[32 + row] + S[64 + row] + S[96 + row];
            const float inv = rsqrtf(ss * (1.0f / 192.0f) + 1.1920929e-07f);
            const int m = m0 + row;
            const int b = m >> 13, rr = (m >> 3) & 1023, gg = m & 7;
            const size_t orow = (((size_t)(b * G_ + gg)) << 10) + rr;
#pragma unroll
            for (int nt = 0; nt < 3; ++nt) {
                const int n = w * 48 + nt * 16 + l15;
                Ynb[orow * E_ + n] = f2bf(acc2[mt][nt][r2] * inv * gvec[n]);
            }
        }
}

// ---- Row attention v7 (R20): 8 waves x 16 q = 128 q-rows per block (512 thr).
// Register-P, tr-read V, ones-row denominator, exp2 domain, split staging
// (tid<256 stages K, tid>=256 stages V). Grid 1536.
__global__ __launch_bounds__(512)
void k_attn2(const unsigned short* __restrict__ QKV, unsigned short* __restrict__ T,
             const int* __restrict__ sep_ptr)
{
    __shared__ __align__(16) unsigned short K_lds[64][40];
    __shared__ __align__(16) unsigned short V_lds[2048];   // [dg(2)][kblk(16)][4][16]

    const int sep = *sep_ptr;
    const int bid = blockIdx.x;
    const int sh = ((bid >> 6) << 3) | (bid & 7);   // same (s,h) => same XCD
    const int qtile = (bid >> 3) & 7;
    const int s = sh / H_, h = sh % H_;
    const int q0 = qtile * 128;

    const int tid = threadIdx.x;
    const int w = tid >> 6;                          // 0..7
    const int lane = tid & 63;
    const int l15 = lane & 15;
    const int g = lane >> 4;

    const int qrow = q0 + w * 16 + l15;
    u16x8 qf = *(const u16x8*)(QKV + ((size_t)s * R_ + qrow) * 576 + h * D_ + g * 8);

    u16x8 onesu;
#pragma unroll
    for (int e = 0; e < 8; ++e) onesu[e] = 0x3F80;  // bf16 1.0
    const bf16x8 onesf = (bf16x8)onesu;

    const bool lo = (q0 < sep);
    const bool hi = (q0 + 128 > sep);
    const int npass = (lo && hi) ? 2 : 1;
    const int nChunk = (sep + 63) >> 6;

    const int st = tid & 255;
    const int skey = st >> 2;
    const int sg   = st & 3;
    const bool stK = (tid < 256);
    const int vst = ((sg >> 1) * 16 + (skey >> 2)) * 64 + (skey & 3) * 16 + (sg & 1) * 8;
    const unsigned vaddr = (unsigned)(size_t)&V_lds[0] + (unsigned)(g * 128 + l15 * 2);

    for (int pass = 0; pass < npass; ++pass) {
        const int hk = (pass == 0) ? (lo ? h : 0) : 0;
        const unsigned short* Kb = QKV + (size_t)s * R_ * 576 + 192 + hk * D_;
        const unsigned short* Vb = QKV + (size_t)s * R_ * 576 + 384 + hk * D_;
        const unsigned short* Sb = stK ? Kb : Vb;

        f32x4 o0 = {0.f, 0.f, 0.f, 0.f};
        f32x4 o1 = {0.f, 0.f, 0.f, 0.f};
        f32x4 o2 = {0.f, 0.f, 0.f, 0.f};   // ones-row: running sum of P

        u16x8 kv = *(const u16x8*)(Sb + (size_t)skey * 576 + sg * 8);

        for (int kc = 0; kc < nChunk; ++kc) {
            const int kbase = kc * 64;
            const bool full = (kbase + 64 <= sep);
            __syncthreads();
            if (stK) *(u16x8*)&K_lds[skey][sg * 8] = kv;
            else     *(u16x8*)&V_lds[vst] = kv;
            __syncthreads();
            if (kc + 1 < nChunk)
                kv = *(const u16x8*)(Sb + (size_t)(kbase + 64 + skey) * 576 + sg * 8);

            f32x4 sc[4];
            const f32x4 zf = {0.f, 0.f, 0.f, 0.f};
            __builtin_amdgcn_s_setprio(1);
#pragma unroll
            for (int t = 0; t < 4; ++t) {
                bf16x8 a = *(const bf16x8*)&K_lds[t * 16 + l15][g * 8];
                sc[t] = __builtin_amdgcn_mfma_f32_16x16x32_bf16(a, (bf16x8)qf, zf, 0, 0, 0);
            }
            __builtin_amdgcn_s_setprio(0);
            if (!full) {
#pragma unroll
                for (int t = 0; t < 4; ++t)
#pragma unroll
                    for (int r = 0; r < 4; ++r)
                        if (kbase + t * 16 + g * 4 + r >= sep) sc[t][r] = -1e30f;
            }
            // P = exp2(s) directly (implicit max = 0); pack to B-fragments.
            bf16x8 pb0, pb1;
            {
                u16x8 p0, p1;
#pragma unroll
                for (int r = 0; r < 4; ++r) {
                    p0[r]     = f2bf(exp2f(sc[0][r]));
                    p0[4 + r] = f2bf(exp2f(sc[1][r]));
                    p1[r]     = f2bf(exp2f(sc[2][r]));
                    p1[4 + r] = f2bf(exp2f(sc[3][r]));
                }
                pb0 = (bf16x8)p0; pb1 = (bf16x8)p1;
            }
            unsigned long long t0, t1, t2, t3, t4, t5, t6, t7;
            asm volatile(
                "ds_read_b64_tr_b16 %0, %8 offset:0\n\t"
                "ds_read_b64_tr_b16 %1, %8 offset:512\n\t"
                "ds_read_b64_tr_b16 %2, %8 offset:1024\n\t"
                "ds_read_b64_tr_b16 %3, %8 offset:1536\n\t"
                "ds_read_b64_tr_b16 %4, %8 offset:2048\n\t"
                "ds_read_b64_tr_b16 %5, %8 offset:2560\n\t"
                "ds_read_b64_tr_b16 %6, %8 offset:3072\n\t"
                "ds_read_b64_tr_b16 %7, %8 offset:3584\n\t"
                "s_waitcnt lgkmcnt(0)"
                : "=&v"(t0), "=&v"(t1), "=&v"(t2), "=&v"(t3),
                  "=&v"(t4), "=&v"(t5), "=&v"(t6), "=&v"(t7)
                : "v"(vaddr)
                : "memory");
            __builtin_amdgcn_sched_barrier(0);
            __builtin_amdgcn_s_setprio(1);
            o0 = __builtin_amdgcn_mfma_f32_16x16x32_bf16(mk8(t0, t1), pb0, o0, 0, 0, 0);
            o1 = __builtin_amdgcn_mfma_f32_16x16x32_bf16(mk8(t4, t5), pb0, o1, 0, 0, 0);
            o2 = __builtin_amdgcn_mfma_f32_16x16x32_bf16(onesf,       pb0, o2, 0, 0, 0);
            o0 = __builtin_amdgcn_mfma_f32_16x16x32_bf16(mk8(t2, t3), pb1, o0, 0, 0, 0);
            o1 = __builtin_amdgcn_mfma_f32_16x16x32_bf16(mk8(t6, t7), pb1, o1, 0, 0, 0);
            o2 = __builtin_amdgcn_mfma_f32_16x16x32_bf16(onesf,       pb1, o2, 0, 0, 0);
            __builtin_amdgcn_s_setprio(0);
        }

        const bool valid = (npass == 1) || (pass == 0 ? (qrow < sep) : (qrow >= sep));
        if (valid) {
            const float inv = 1.f / o2[0];
            unsigned short* tp = T + ((size_t)s * R_ + qrow) * E_ + h * D_;
            ushort4 v0, v1;
            v0.x = f2bf(o0[0] * inv); v0.y = f2bf(o0[1] * inv);
            v0.z = f2bf(o0[2] * inv); v0.w = f2bf(o0[3] * inv);
            v1.x = f2bf(o1[0] * inv); v1.y = f2bf(o1[1] * inv);
            v1.z = f2bf(o1[2] * inv); v1.w = f2bf(o1[3] * inv);
            *(ushort4*)(tp + g * 4)      = v0;
            *(ushort4*)(tp + 16 + g * 4) = v1;
        }
    }
}

extern "C" void kernel_launch(void* const* d_in, const int* in_sizes, int n_in,
                              void* d_out, int out_size, void* d_ws, size_t ws_size,
                              hipStream_t stream) {
    const float* hidden = (const float*)d_in[0];
    const float* Wq1 = (const float*)d_in[1];
    const float* Wk1 = (const float*)d_in[2];
    const float* Wv1 = (const float*)d_in[3];
    const float* Wo1 = (const float*)d_in[4];
    const float* Wq2 = (const float*)d_in[5];
    const float* Wk2 = (const float*)d_in[6];
    const float* Wv2 = (const float*)d_in[7];
    const float* Wo2 = (const float*)d_in[8];
    const float* W1  = (const float*)d_in[9];
    const float* W2  = (const float*)d_in[10];
    const float* g1  = (const float*)d_in[11];
    const float* g2  = (const float*)d_in[12];
    const float* g3  = (const float*)d_in[13];
    const int*   sep = (const int*)d_in[14];

    float* Xout = (float*)d_out;                    // final f32 X-layout output
    unsigned short* ws = (unsigned short*)d_ws;
    unsigned short* QKVb = ws;                      // [M][576] bf16 (aliases H1 [M][384])
    unsigned short* Tb   = QKVb + (size_t)M_ * 576;
    unsigned short* Ynb  = Tb + NBUF;               // rms-g1 output, XR layout
    unsigned short* Xcb  = Ynb + NBUF;              // rms-g2 output, X layout
    unsigned short* Xb   = Xcb + NBUF;              // inter-layer residual (layers 0-2)
    unsigned short* Wt   = Xb + NBUF;
    unsigned short* H1b  = QKVb;

    const dim3 blk(256);
    const dim3 blk512(512);
    const dim3 gQKV(M_ / 64, 3);
    const dim3 gW1(M_ / 64, 2);
    const dim3 g32(M_ / 32);                        // 1024 blocks (featblock)
    const dim3 g64(M_ / 64);                        // 512 blocks (rms64)
    const dim3 gA2(32 * H_ * 8);                    // (s,h) x 8 q-tiles of 128 rows

    k_convw_all<<<dim3(432 * L_), blk, 0, stream>>>(Wq1, Wk1, Wv1, Wo1, Wq2, Wk2, Wv2, Wo2, W1, W2, Wt);

    for (int i = 0; i < L_; ++i) {
        unsigned short* wl = Wt + (size_t)i * WPL;
        const unsigned short* wqkv1 = wl;
        const unsigned short* wo1   = wl + 3 * (size_t)E_ * E_;
        const unsigned short* wqkv2 = wl + 4 * (size_t)E_ * E_;
        const unsigned short* wo2   = wl + 7 * (size_t)E_ * E_;
        const unsigned short* w1    = wl + 8 * (size_t)E_ * E_;
        const unsigned short* w2    = wl + 8 * (size_t)E_ * E_ + (size_t)E_ * F_;
        const float* g1i = g1 + (size_t)i * E_;
        const float* g2i = g2 + (size_t)i * E_;
        const float* g3i = g3 + (size_t)i * E_;

        // --- fused feature-attention block: X/hidden -> Ynb (XR) ---
        if (i == 0)
            k_featblock<true><<<g32, blk, 0, stream>>>(hidden, wqkv1, wo1, g1i, Ynb);
        else
            k_featblock<false><<<g32, blk, 0, stream>>>(Xb, wqkv1, wo1, g1i, Ynb);
        // --- row attention block ---
        k_gemm_mfma<true, 0><<<gQKV, blk, 0, stream>>>(Ynb, wqkv2, QKVb, 576, E_);
        k_attn2<<<gA2, blk512, 0, stream>>>(QKVb, Tb, sep);
        k_gemm_rms64<true, 3><<<g64, blk512, 0, stream>>>(Tb, wo2, Ynb, g2i, Xcb, E_);
        // --- MLP block ---
        k_gemm_mfma<true, 1><<<gW1, blk, 0, stream>>>(Xcb, w1, H1b, F_, E_);
        if (i == L_ - 1)
            k_gemm_rms64<true, 4><<<g64, blk512, 0, stream>>>(H1b, w2, Xcb, g3i, Xout, F_);
        else
            k_gemm_rms64<true, 5><<<g64, blk512, 0, stream>>>(H1b, w2, Xcb, g3i, Xb, F_);
    }
}

// Round 22
// 561.312 us; speedup vs baseline: 1.1131x; 1.0212x over previous
//
#include <hip/hip_runtime.h>
#include <hip/hip_bf16.h>
#include <math.h>

#define B_ 4
#define R_ 1024
#define G_ 8
#define E_ 192
#define H_ 6
#define D_ 32
#define L_ 4
#define F_ 384
#define M_ (B_*R_*G_)              // 32768 rows
static const size_t NBUF = (size_t)M_ * E_;       // 6291456 elems
static const size_t WPL  = 8 * (size_t)E_ * E_ + 2 * (size_t)E_ * F_;  // bf16/layer

typedef __attribute__((ext_vector_type(8))) short bf16x8;
typedef __attribute__((ext_vector_type(8))) unsigned short u16x8;
typedef __attribute__((ext_vector_type(4))) float f32x4;

__device__ __forceinline__ float gelu_exact(float x) {
    return 0.5f * x * (1.0f + erff(x * 0.7071067811865475f));
}
__device__ __forceinline__ unsigned short f2bf(float f) {
    __hip_bfloat16 h = __float2bfloat16(f);
    return *(unsigned short*)&h;
}
__device__ __forceinline__ float bf2f(unsigned short h) {
    union { unsigned u; float f; } v; v.u = ((unsigned)h) << 16; return v.f;
}
__device__ __forceinline__ bf16x8 mk8(unsigned long long lo, unsigned long long hi) {
    union { unsigned long long q[2]; bf16x8 v; } u;
    u.q[0] = lo; u.q[1] = hi; return u.v;
}

// ---- one-shot: transpose+convert all weights to Wt[N][K] bf16.
// Scale folds: Wq1 *= 1/sqrt(D); Wq2 *= log2(e)/sqrt(D)  (attn2 runs in exp2 domain).
__global__ __launch_bounds__(256)
void k_convw_all(const float* __restrict__ Wq1, const float* __restrict__ Wk1,
                 const float* __restrict__ Wv1, const float* __restrict__ Wo1,
                 const float* __restrict__ Wq2, const float* __restrict__ Wk2,
                 const float* __restrict__ Wv2, const float* __restrict__ Wo2,
                 const float* __restrict__ W1,  const float* __restrict__ W2,
                 unsigned short* __restrict__ Wt)
{
    const int t = blockIdx.x;
    const int layer = t / 432;
    const int r = t % 432;
    const float* src; unsigned short* dst; int K, N; float scale = 1.f; int tile;
    if (r < 288) {
        const int w = r / 36; tile = r % 36; K = E_; N = E_;
        const float* tab[8] = {Wq1, Wk1, Wv1, Wo1, Wq2, Wk2, Wv2, Wo2};
        src = tab[w] + (size_t)layer * E_ * E_;
        dst = Wt + (size_t)layer * WPL + (size_t)w * E_ * E_;
        if (w == 0) scale = 0.17677669529663687f;                       // 1/sqrt(32)
        if (w == 4) scale = 0.17677669529663687f * 1.4426950408889634f; // log2e/sqrt(32)
    } else if (r < 360) {
        tile = r - 288; K = E_; N = F_;
        src = W1 + (size_t)layer * E_ * F_;
        dst = Wt + (size_t)layer * WPL + 8 * (size_t)E_ * E_;
    } else {
        tile = r - 360; K = F_; N = E_;
        src = W2 + (size_t)layer * E_ * F_;
        dst = Wt + (size_t)layer * WPL + 8 * (size_t)E_ * E_ + (size_t)E_ * F_;
    }
    const int ntx = N / 32;
    const int kb = (tile / ntx) * 32, nb = (tile % ntx) * 32;
    __shared__ float tl[32][33];
    const int tx = threadIdx.x & 31, ty = threadIdx.x >> 5;
    for (int i2 = 0; i2 < 32; i2 += 8)
        tl[ty + i2][tx] = src[(size_t)(kb + ty + i2) * N + nb + tx];
    __syncthreads();
    for (int i2 = 0; i2 < 32; i2 += 8)
        dst[(size_t)(nb + ty + i2) * K + kb + tx] = f2bf(tl[tx][ty + i2] * scale);
}

// ---- MFMA GEMM v2: tile 128 x 192, BK=32, 8 waves (512 thr), grid M/128.
// Wave w: m-half (w&1), col-quarter (w>>1) -> per-wave work identical to the
// 4-wave form (4 m-tiles x 3 n-tiles). B panel staged once per 128 rows (was
// twice); staging split: all stage A (1 unit) + B rows 0..127 (1 unit);
// tid<256 also stage B rows 128..191. Reg-prefetch pipeline retained.
// EPI: 0 = store bf16 at [m][n0+n], ldc; 1 = gelu -> bf16, ldc.
template<bool ABF16, int EPI>
__global__ __launch_bounds__(512)
void k_gemm_mfma(const void* __restrict__ Ap, const unsigned short* __restrict__ Wt,
                 void* __restrict__ Cp, int ldc, int K)
{
    __shared__ unsigned short As[128][40];
    __shared__ unsigned short Bs[192][40];
    const int m0 = blockIdx.x * 128;
    const int n0 = blockIdx.y * 192;
    const int tid = threadIdx.x;
    const int w = tid >> 6, lane = tid & 63, l15 = lane & 15, g = lane >> 4;
    const int mh = w & 1, nq = w >> 1;
    const int arow = tid >> 2, akoff = (tid & 3) << 3;        // A rows 0..127: all
    const int st = tid & 255;
    const int b1row = 128 + (st >> 2), b1off = (st & 3) << 3; // B rows 128..191: tid<256
    f32x4 acc[4][3];
#pragma unroll
    for (int mt = 0; mt < 4; ++mt)
#pragma unroll
        for (int nt = 0; nt < 3; ++nt)
#pragma unroll
            for (int r2 = 0; r2 < 4; ++r2) acc[mt][nt][r2] = 0.f;
    const int nK = K >> 5;

    float4 ax, ay; u16x8 av; u16x8 bv0, bv1;
    auto gload = [&](int k0) {
        if (ABF16) {
            av = *(const u16x8*)((const unsigned short*)Ap + (size_t)(m0 + arow) * K + k0 + akoff);
        } else {
            const float* ap = (const float*)Ap + (size_t)(m0 + arow) * K + k0 + akoff;
            ax = *(const float4*)ap; ay = *(const float4*)(ap + 4);
        }
        bv0 = *(const u16x8*)(Wt + (size_t)(n0 + arow) * K + k0 + akoff);
        if (tid < 256)
            bv1 = *(const u16x8*)(Wt + (size_t)(n0 + b1row) * K + k0 + b1off);
    };
    auto swrite = [&]() {
        u16x8 aw;
        if (ABF16) aw = av;
        else {
            aw[0] = f2bf(ax.x); aw[1] = f2bf(ax.y); aw[2] = f2bf(ax.z); aw[3] = f2bf(ax.w);
            aw[4] = f2bf(ay.x); aw[5] = f2bf(ay.y); aw[6] = f2bf(ay.z); aw[7] = f2bf(ay.w);
        }
        *(u16x8*)&As[arow][akoff] = aw;
        *(u16x8*)&Bs[arow][akoff] = bv0;
        if (tid < 256) *(u16x8*)&Bs[b1row][b1off] = bv1;
    };

    gload(0);
    for (int kc = 0; kc < nK; ++kc) {
        __syncthreads();
        swrite();
        __syncthreads();
        if (kc + 1 < nK) gload((kc + 1) << 5);
        bf16x8 af[4], bfr[3];
#pragma unroll
        for (int mt = 0; mt < 4; ++mt) af[mt] = *(const bf16x8*)&As[mh * 64 + mt * 16 + l15][g * 8];
#pragma unroll
        for (int nt = 0; nt < 3; ++nt) bfr[nt] = *(const bf16x8*)&Bs[nq * 48 + nt * 16 + l15][g * 8];
#pragma unroll
        for (int mt = 0; mt < 4; ++mt)
#pragma unroll
            for (int nt = 0; nt < 3; ++nt)
                acc[mt][nt] = __builtin_amdgcn_mfma_f32_16x16x32_bf16(af[mt], bfr[nt], acc[mt][nt], 0, 0, 0);
    }

#pragma unroll
    for (int mt = 0; mt < 4; ++mt)
#pragma unroll
        for (int r2 = 0; r2 < 4; ++r2) {
            const int m = m0 + mh * 64 + mt * 16 + g * 4 + r2;
#pragma unroll
            for (int nt = 0; nt < 3; ++nt) {
                const int n = nq * 48 + nt * 16 + l15;
                float v = acc[mt][nt][r2];
                if (EPI == 1) v = gelu_exact(v);
                ((unsigned short*)Cp)[(size_t)m * ldc + n0 + n] = f2bf(v);
            }
        }
}

// ---- MFMA GEMM + residual + row-RMSNorm v2 (R21): tile 64 x 192, 8 waves.
// EPI: 3 = ->bf16, transpose XR->X; 4 = ->f32; 5 = ->bf16.
template<bool RESBF16, int EPI>
__global__ __launch_bounds__(512)
void k_gemm_rms64(const unsigned short* __restrict__ Ap, const unsigned short* __restrict__ Wt,
                  const void* __restrict__ Resp, const float* __restrict__ gvec,
                  void* __restrict__ Cp, int K)
{
    __shared__ unsigned short As[64][40];
    __shared__ unsigned short Bs[192][40];
    __shared__ float ss_red[8][16];
    const int m0 = blockIdx.x * 64;
    const int tid = threadIdx.x;
    const int w = tid >> 6, lane = tid & 63, l15 = lane & 15, g = lane >> 4;
    const int mt = w & 3, nh = w >> 2;
    const int st = tid & 255;
    const int arow = st >> 2, akoff = (st & 3) << 3;          // A: tid>=256
    const int b0row = tid >> 2, b0off = (tid & 3) << 3;       // B rows 0..127: all
    const int b1row = 128 + (st >> 2), b1off = (st & 3) << 3; // B rows 128..191: tid<256
    f32x4 acc[6];
#pragma unroll
    for (int nt = 0; nt < 6; ++nt)
#pragma unroll
        for (int r2 = 0; r2 < 4; ++r2) acc[nt][r2] = 0.f;
    const int nK = K >> 5;

    u16x8 av, bv0, bv1;
    auto gload = [&](int k0) {
        if (tid >= 256)
            av = *(const u16x8*)(Ap + (size_t)(m0 + arow) * K + k0 + akoff);
        bv0 = *(const u16x8*)(Wt + (size_t)b0row * K + k0 + b0off);
        if (tid < 256)
            bv1 = *(const u16x8*)(Wt + (size_t)b1row * K + k0 + b1off);
    };
    auto swrite = [&]() {
        if (tid >= 256) *(u16x8*)&As[arow][akoff] = av;
        *(u16x8*)&Bs[b0row][b0off] = bv0;
        if (tid < 256) *(u16x8*)&Bs[b1row][b1off] = bv1;
    };

    gload(0);
    for (int kc = 0; kc < nK; ++kc) {
        __syncthreads();
        swrite();
        __syncthreads();
        if (kc + 1 < nK) gload((kc + 1) << 5);
        bf16x8 af = *(const bf16x8*)&As[mt * 16 + l15][g * 8];
        bf16x8 bfr[6];
#pragma unroll
        for (int nt = 0; nt < 6; ++nt) bfr[nt] = *(const bf16x8*)&Bs[nh * 96 + nt * 16 + l15][g * 8];
#pragma unroll
        for (int nt = 0; nt < 6; ++nt)
            acc[nt] = __builtin_amdgcn_mfma_f32_16x16x32_bf16(af, bfr[nt], acc[nt], 0, 0, 0);
    }

    float ssp[4] = {0.f, 0.f, 0.f, 0.f};
#pragma unroll
    for (int r2 = 0; r2 < 4; ++r2) {
        const int m = m0 + mt * 16 + g * 4 + r2;
#pragma unroll
        for (int nt = 0; nt < 6; ++nt) {
            const int n = nh * 96 + nt * 16 + l15;
            float rres = RESBF16 ? bf2f(((const unsigned short*)Resp)[(size_t)m * E_ + n])
                                 : ((const float*)Resp)[(size_t)m * E_ + n];
            float v = acc[nt][r2] + rres;
            acc[nt][r2] = v;
            ssp[r2] += v * v;
        }
    }
#pragma unroll
    for (int off = 1; off < 16; off <<= 1)
#pragma unroll
        for (int r2 = 0; r2 < 4; ++r2)
            ssp[r2] += __shfl_xor(ssp[r2], off);
    if (l15 == 0) {
#pragma unroll
        for (int r2 = 0; r2 < 4; ++r2)
            ss_red[w][g * 4 + r2] = ssp[r2];
    }
    __syncthreads();
#pragma unroll
    for (int r2 = 0; r2 < 4; ++r2) {
        const int lr = g * 4 + r2;
        const float ss = ss_red[mt][lr] + ss_red[4 + mt][lr];
        const float inv = rsqrtf(ss * (1.0f / 192.0f) + 1.1920929e-07f);
        const int m = m0 + mt * 16 + lr;
        size_t orow;
        if (EPI == 3) {        // XR -> X
            const int b = m >> 13, gg = (m >> 10) & 7, rr = m & 1023;
            orow = ((((size_t)b << 10) + rr) << 3) + gg;
        } else {
            orow = m;
        }
#pragma unroll
        for (int nt = 0; nt < 6; ++nt) {
            const int n = nh * 96 + nt * 16 + l15;
            const float v = acc[nt][r2] * inv * gvec[n];
            if (EPI == 4) ((float*)Cp)[orow * E_ + n] = v;
            else          ((unsigned short*)Cp)[orow * E_ + n] = f2bf(v);
        }
    }
}

// ---- Fused feature-attention block v5 (R17 best): per-wave-private B slices
// with XOR-swizzled UNPADDED layout; LDS 50.2 KB => 3 blocks/CU; 5 barriers.
template<bool AF32>
__global__ __launch_bounds__(256)
void k_featblock(const void* __restrict__ Xin, const unsigned short* __restrict__ Wqkv,
                 const unsigned short* __restrict__ Wo, const float* __restrict__ gvec,
                 unsigned short* __restrict__ Ynb)
{
    __shared__ __align__(16) unsigned short raw[18688];      // 37376 B (QKVl is max user)
    __shared__ __align__(16) unsigned short AsTl[32][200];   // 12800 B: A (ph1) -> Tl (ph2/3)

    unsigned short (*QKVl)[584] = (unsigned short (*)[584])raw;
    const int m0 = blockIdx.x * 32;
    const int tid = threadIdx.x;
    const int w = tid >> 6, lane = tid & 63, l15 = lane & 15, g = lane >> 4;

    // ---- stage A once (32 x 192, coalesced) ----
#pragma unroll
    for (int j = 0; j < 3; ++j) {
        const int v = tid + 256 * j;          // 0..767
        const int row = v / 24, ch = v % 24;  // 24 chunks of 8 elems per row
        u16x8 aw;
        if (AF32) {
            const float* ap = (const float*)Xin + (size_t)(m0 + row) * E_ + ch * 8;
            float4 x = *(const float4*)ap, y = *(const float4*)(ap + 4);
            aw[0] = f2bf(x.x); aw[1] = f2bf(x.y); aw[2] = f2bf(x.z); aw[3] = f2bf(x.w);
            aw[4] = f2bf(y.x); aw[5] = f2bf(y.y); aw[6] = f2bf(y.z); aw[7] = f2bf(y.w);
        } else {
            aw = *(const u16x8*)((const unsigned short*)Xin + (size_t)(m0 + row) * E_ + ch * 8);
        }
        *(u16x8*)&AsTl[row][ch * 8] = aw;
    }
    __syncthreads();   // B1: A visible to all waves

    // ---- phase 1: QKV = A @ Wqkv^T, per-wave swizzled B slices, no barriers ----
    f32x4 acc[2][9];
#pragma unroll
    for (int mt = 0; mt < 2; ++mt)
#pragma unroll
        for (int nt = 0; nt < 9; ++nt)
#pragma unroll
            for (int r2 = 0; r2 < 4; ++r2) acc[mt][nt][r2] = 0.f;

    unsigned short* slice1 = raw + w * 4608;          // [144][32] swizzled
    u16x8 bv[9];
    auto gload1 = [&](int k0) {
#pragma unroll
        for (int j = 0; j < 9; ++j) {
            const int v = lane + 64 * j;
            bv[j] = *(const u16x8*)(Wqkv + (size_t)(w * 144 + (v >> 2)) * E_ + k0 + ((v & 3) << 3));
        }
    };
    auto swrite1 = [&]() {
#pragma unroll
        for (int j = 0; j < 9; ++j) {
            const int v = lane + 64 * j;
            const int row = v >> 2;
            const int pos = (v & 3) ^ (row & 3);      // XOR swizzle
            *(u16x8*)&slice1[row * 32 + pos * 8] = bv[j];
        }
    };
    const int rb1 = g ^ (l15 & 3);                    // read-side swizzled block

    gload1(0);
    swrite1();
    gload1(32);
#pragma unroll
    for (int kc = 0; kc < 6; ++kc) {
        const int k0 = kc << 5;
        bf16x8 af0 = *(const bf16x8*)&AsTl[l15][k0 + g * 8];
        bf16x8 af1 = *(const bf16x8*)&AsTl[16 + l15][k0 + g * 8];
        bf16x8 bfr[9];
#pragma unroll
        for (int nt = 0; nt < 9; ++nt)
            bfr[nt] = *(const bf16x8*)&slice1[(nt * 16 + l15) * 32 + rb1 * 8];
#pragma unroll
        for (int nt = 0; nt < 9; ++nt) {
            acc[0][nt] = __builtin_amdgcn_mfma_f32_16x16x32_bf16(af0, bfr[nt], acc[0][nt], 0, 0, 0);
            acc[1][nt] = __builtin_amdgcn_mfma_f32_16x16x32_bf16(af1, bfr[nt], acc[1][nt], 0, 0, 0);
        }
        if (kc + 1 < 6) swrite1();                 // bv holds kc+1 (in-order LDS)
        if (kc + 2 < 6) gload1((kc + 2) << 5);
    }
    __syncthreads();   // B2: all waves' Bq reads done before QKVl overlay

    // spill QKV to QKVl (wave w writes its 144-col slice of all 32 rows)
#pragma unroll
    for (int mt = 0; mt < 2; ++mt)
#pragma unroll
        for (int r2 = 0; r2 < 4; ++r2)
#pragma unroll
            for (int nt = 0; nt < 9; ++nt)
                QKVl[mt * 16 + g * 4 + r2][w * 144 + nt * 16 + l15] = f2bf(acc[mt][nt][r2]);

    // prefetch phase-3 chunk-0 weights (latency hides under attn1)
    u16x8 bo[3];
    auto gload3 = [&](int k0) {
#pragma unroll
        for (int j = 0; j < 3; ++j) {
            const int v = lane + 64 * j;
            bo[j] = *(const u16x8*)(Wo + (size_t)(w * 48 + (v >> 2)) * E_ + k0 + ((v & 3) << 3));
        }
    };
    gload3(0);
    __syncthreads();   // B3: QKVl complete

    // ---- phase 2: attn1 (wave w = seq w; lane = i*8+j over G=8) ----
    {
        const int i = lane >> 3, j = lane & 7;
        const int r0 = w * 8;
#pragma unroll
        for (int h = 0; h < 6; ++h) {
            float s = 0.f;
#pragma unroll
            for (int d8 = 0; d8 < 4; ++d8) {
                u16x8 qv = *(const u16x8*)&QKVl[r0 + i][h * 32 + d8 * 8];
                u16x8 kv = *(const u16x8*)&QKVl[r0 + j][192 + h * 32 + d8 * 8];
#pragma unroll
                for (int e = 0; e < 8; ++e) s += bf2f(qv[e]) * bf2f(kv[e]);
            }
            float mx = s;
#pragma unroll
            for (int off = 1; off < 8; off <<= 1) mx = fmaxf(mx, __shfl_xor(mx, off));
            float p = __expf(s - mx);
            float sum = p;
#pragma unroll
            for (int off = 1; off < 8; off <<= 1) sum += __shfl_xor(sum, off);
            p /= sum;
            const int base = lane & ~7;
            float o0 = 0.f, o1 = 0.f, o2 = 0.f, o3 = 0.f;
#pragma unroll
            for (int jj = 0; jj < 8; ++jj) {
                float pj = __shfl(p, base + jj);
                ushort4 vv = *(const ushort4*)&QKVl[r0 + jj][384 + h * 32 + j * 4];
                o0 += pj * bf2f(vv.x); o1 += pj * bf2f(vv.y);
                o2 += pj * bf2f(vv.z); o3 += pj * bf2f(vv.w);
            }
            ushort4 ov; ov.x = f2bf(o0); ov.y = f2bf(o1); ov.z = f2bf(o2); ov.w = f2bf(o3);
            *(ushort4*)&AsTl[r0 + i][h * 32 + j * 4] = ov;   // Tl overlays A
        }
    }

    // preload epilogue residual (hides under phase 3)
    float rv[2][4][3];
#pragma unroll
    for (int mt = 0; mt < 2; ++mt)
#pragma unroll
        for (int r2 = 0; r2 < 4; ++r2) {
            const int m = m0 + mt * 16 + g * 4 + r2;
#pragma unroll
            for (int nt = 0; nt < 3; ++nt) {
                const int n = w * 48 + nt * 16 + l15;
                rv[mt][r2][nt] = AF32 ? ((const float*)Xin)[(size_t)m * E_ + n]
                                      : bf2f(((const unsigned short*)Xin)[(size_t)m * E_ + n]);
            }
        }
    __syncthreads();   // B4: Tl complete; QKVl reads done before Bo overlay

    // ---- phase 3: T @ wo1^T, per-wave swizzled Bo slices, no barriers ----
    unsigned short* slice3 = raw + w * 1536;          // [48][32] swizzled
    f32x4 acc2[2][3];
#pragma unroll
    for (int mt = 0; mt < 2; ++mt)
#pragma unroll
        for (int nt = 0; nt < 3; ++nt)
#pragma unroll
            for (int r2 = 0; r2 < 4; ++r2) acc2[mt][nt][r2] = 0.f;

    auto swrite3 = [&]() {
#pragma unroll
        for (int j = 0; j < 3; ++j) {
            const int v = lane + 64 * j;
            const int row = v >> 2;
            const int pos = (v & 3) ^ (row & 3);
            *(u16x8*)&slice3[row * 32 + pos * 8] = bo[j];
        }
    };
    swrite3();
    gload3(32);
#pragma unroll
    for (int kc = 0; kc < 6; ++kc) {
        const int k0 = kc << 5;
        bf16x8 af0 = *(const bf16x8*)&AsTl[l15][k0 + g * 8];
        bf16x8 af1 = *(const bf16x8*)&AsTl[16 + l15][k0 + g * 8];
        bf16x8 bfr[3];
#pragma unroll
        for (int nt = 0; nt < 3; ++nt)
            bfr[nt] = *(const bf16x8*)&slice3[(nt * 16 + l15) * 32 + rb1 * 8];
#pragma unroll
        for (int nt = 0; nt < 3; ++nt) {
            acc2[0][nt] = __builtin_amdgcn_mfma_f32_16x16x32_bf16(af0, bfr[nt], acc2[0][nt], 0, 0, 0);
            acc2[1][nt] = __builtin_amdgcn_mfma_f32_16x16x32_bf16(af1, bfr[nt], acc2[1][nt], 0, 0, 0);
        }
        if (kc + 1 < 6) swrite3();
        if (kc + 2 < 6) gload3((kc + 2) << 5);
    }

    // ---- epilogue: +res(preloaded), row-RMS*g1, transpose X->XR ----
    float* S = (float*)(raw + 6400);   // beyond Bo slices (elems 0..6143)
    float ssp[2][4] = {};
#pragma unroll
    for (int mt = 0; mt < 2; ++mt)
#pragma unroll
        for (int r2 = 0; r2 < 4; ++r2) {
#pragma unroll
            for (int nt = 0; nt < 3; ++nt) {
                float v = acc2[mt][nt][r2] + rv[mt][r2][nt];
                acc2[mt][nt][r2] = v;
                ssp[mt][r2] += v * v;
            }
        }
#pragma unroll
    for (int off = 1; off < 16; off <<= 1)
#pragma unroll
        for (int mt = 0; mt < 2; ++mt)
#pragma unroll
            for (int r2 = 0; r2 < 4; ++r2)
                ssp[mt][r2] += __shfl_xor(ssp[mt][r2], off);
    if (l15 == 0) {
#pragma unroll
        for (int mt = 0; mt < 2; ++mt)
#pragma unroll
            for (int r2 = 0; r2 < 4; ++r2)
                S[w * 32 + mt * 16 + g * 4 + r2] = ssp[mt][r2];
    }
    __syncthreads();   // B5
#pragma unroll
    for (int mt = 0; mt < 2; ++mt)
#pragma unroll
        for (int r2 = 0; r2 < 4; ++r2) {
            const int row = mt * 16 + g * 4 + r2;
            const float ss = S[row] + S[32 + row] + S[64 + row] + S[96 + row];
            const float inv = rsqrtf(ss * (1.0f / 192.0f) + 1.1920929e-07f);
            const int m = m0 + row;
            const int b = m >> 13, rr = (m >> 3) & 1023, gg = m & 7;
            const size_t orow = (((size_t)(b * G_ + gg)) << 10) + rr;
#pragma unroll
            for (int nt = 0; nt < 3; ++nt) {
                const int n = w * 48 + nt * 16 + l15;
                Ynb[orow * E_ + n] = f2bf(acc2[mt][nt][r2] * inv * gvec[n]);
            }
        }
}

// ---- Row attention v7 (R20): 8 waves x 16 q = 128 q-rows per block (512 thr).
// Register-P, tr-read V, ones-row denominator, exp2 domain, split staging
// (tid<256 stages K, tid>=256 stages V). Grid 1536.
__global__ __launch_bounds__(512)
void k_attn2(const unsigned short* __restrict__ QKV, unsigned short* __restrict__ T,
             const int* __restrict__ sep_ptr)
{
    __shared__ __align__(16) unsigned short K_lds[64][40];
    __shared__ __align__(16) unsigned short V_lds[2048];   // [dg(2)][kblk(16)][4][16]

    const int sep = *sep_ptr;
    const int bid = blockIdx.x;
    const int sh = ((bid >> 6) << 3) | (bid & 7);   // same (s,h) => same XCD
    const int qtile = (bid >> 3) & 7;
    const int s = sh / H_, h = sh % H_;
    const int q0 = qtile * 128;

    const int tid = threadIdx.x;
    const int w = tid >> 6;                          // 0..7
    const int lane = tid & 63;
    const int l15 = lane & 15;
    const int g = lane >> 4;

    const int qrow = q0 + w * 16 + l15;
    u16x8 qf = *(const u16x8*)(QKV + ((size_t)s * R_ + qrow) * 576 + h * D_ + g * 8);

    u16x8 onesu;
#pragma unroll
    for (int e = 0; e < 8; ++e) onesu[e] = 0x3F80;  // bf16 1.0
    const bf16x8 onesf = (bf16x8)onesu;

    const bool lo = (q0 < sep);
    const bool hi = (q0 + 128 > sep);
    const int npass = (lo && hi) ? 2 : 1;
    const int nChunk = (sep + 63) >> 6;

    const int st = tid & 255;
    const int skey = st >> 2;
    const int sg   = st & 3;
    const bool stK = (tid < 256);
    const int vst = ((sg >> 1) * 16 + (skey >> 2)) * 64 + (skey & 3) * 16 + (sg & 1) * 8;
    const unsigned vaddr = (unsigned)(size_t)&V_lds[0] + (unsigned)(g * 128 + l15 * 2);

    for (int pass = 0; pass < npass; ++pass) {
        const int hk = (pass == 0) ? (lo ? h : 0) : 0;
        const unsigned short* Kb = QKV + (size_t)s * R_ * 576 + 192 + hk * D_;
        const unsigned short* Vb = QKV + (size_t)s * R_ * 576 + 384 + hk * D_;
        const unsigned short* Sb = stK ? Kb : Vb;

        f32x4 o0 = {0.f, 0.f, 0.f, 0.f};
        f32x4 o1 = {0.f, 0.f, 0.f, 0.f};
        f32x4 o2 = {0.f, 0.f, 0.f, 0.f};   // ones-row: running sum of P

        u16x8 kv = *(const u16x8*)(Sb + (size_t)skey * 576 + sg * 8);

        for (int kc = 0; kc < nChunk; ++kc) {
            const int kbase = kc * 64;
            const bool full = (kbase + 64 <= sep);
            __syncthreads();
            if (stK) *(u16x8*)&K_lds[skey][sg * 8] = kv;
            else     *(u16x8*)&V_lds[vst] = kv;
            __syncthreads();
            if (kc + 1 < nChunk)
                kv = *(const u16x8*)(Sb + (size_t)(kbase + 64 + skey) * 576 + sg * 8);

            f32x4 sc[4];
            const f32x4 zf = {0.f, 0.f, 0.f, 0.f};
            __builtin_amdgcn_s_setprio(1);
#pragma unroll
            for (int t = 0; t < 4; ++t) {
                bf16x8 a = *(const bf16x8*)&K_lds[t * 16 + l15][g * 8];
                sc[t] = __builtin_amdgcn_mfma_f32_16x16x32_bf16(a, (bf16x8)qf, zf, 0, 0, 0);
            }
            __builtin_amdgcn_s_setprio(0);
            if (!full) {
#pragma unroll
                for (int t = 0; t < 4; ++t)
#pragma unroll
                    for (int r = 0; r < 4; ++r)
                        if (kbase + t * 16 + g * 4 + r >= sep) sc[t][r] = -1e30f;
            }
            // P = exp2(s) directly (implicit max = 0); pack to B-fragments.
            bf16x8 pb0, pb1;
            {
                u16x8 p0, p1;
#pragma unroll
                for (int r = 0; r < 4; ++r) {
                    p0[r]     = f2bf(exp2f(sc[0][r]));
                    p0[4 + r] = f2bf(exp2f(sc[1][r]));
                    p1[r]     = f2bf(exp2f(sc[2][r]));
                    p1[4 + r] = f2bf(exp2f(sc[3][r]));
                }
                pb0 = (bf16x8)p0; pb1 = (bf16x8)p1;
            }
            unsigned long long t0, t1, t2, t3, t4, t5, t6, t7;
            asm volatile(
                "ds_read_b64_tr_b16 %0, %8 offset:0\n\t"
                "ds_read_b64_tr_b16 %1, %8 offset:512\n\t"
                "ds_read_b64_tr_b16 %2, %8 offset:1024\n\t"
                "ds_read_b64_tr_b16 %3, %8 offset:1536\n\t"
                "ds_read_b64_tr_b16 %4, %8 offset:2048\n\t"
                "ds_read_b64_tr_b16 %5, %8 offset:2560\n\t"
                "ds_read_b64_tr_b16 %6, %8 offset:3072\n\t"
                "ds_read_b64_tr_b16 %7, %8 offset:3584\n\t"
                "s_waitcnt lgkmcnt(0)"
                : "=&v"(t0), "=&v"(t1), "=&v"(t2), "=&v"(t3),
                  "=&v"(t4), "=&v"(t5), "=&v"(t6), "=&v"(t7)
                : "v"(vaddr)
                : "memory");
            __builtin_amdgcn_sched_barrier(0);
            __builtin_amdgcn_s_setprio(1);
            o0 = __builtin_amdgcn_mfma_f32_16x16x32_bf16(mk8(t0, t1), pb0, o0, 0, 0, 0);
            o1 = __builtin_amdgcn_mfma_f32_16x16x32_bf16(mk8(t4, t5), pb0, o1, 0, 0, 0);
            o2 = __builtin_amdgcn_mfma_f32_16x16x32_bf16(onesf,       pb0, o2, 0, 0, 0);
            o0 = __builtin_amdgcn_mfma_f32_16x16x32_bf16(mk8(t2, t3), pb1, o0, 0, 0, 0);
            o1 = __builtin_amdgcn_mfma_f32_16x16x32_bf16(mk8(t6, t7), pb1, o1, 0, 0, 0);
            o2 = __builtin_amdgcn_mfma_f32_16x16x32_bf16(onesf,       pb1, o2, 0, 0, 0);
            __builtin_amdgcn_s_setprio(0);
        }

        const bool valid = (npass == 1) || (pass == 0 ? (qrow < sep) : (qrow >= sep));
        if (valid) {
            const float inv = 1.f / o2[0];
            unsigned short* tp = T + ((size_t)s * R_ + qrow) * E_ + h * D_;
            ushort4 v0, v1;
            v0.x = f2bf(o0[0] * inv); v0.y = f2bf(o0[1] * inv);
            v0.z = f2bf(o0[2] * inv); v0.w = f2bf(o0[3] * inv);
            v1.x = f2bf(o1[0] * inv); v1.y = f2bf(o1[1] * inv);
            v1.z = f2bf(o1[2] * inv); v1.w = f2bf(o1[3] * inv);
            *(ushort4*)(tp + g * 4)      = v0;
            *(ushort4*)(tp + 16 + g * 4) = v1;
        }
    }
}

extern "C" void kernel_launch(void* const* d_in, const int* in_sizes, int n_in,
                              void* d_out, int out_size, void* d_ws, size_t ws_size,
                              hipStream_t stream) {
    const float* hidden = (const float*)d_in[0];
    const float* Wq1 = (const float*)d_in[1];
    const float* Wk1 = (const float*)d_in[2];
    const float* Wv1 = (const float*)d_in[3];
    const float* Wo1 = (const float*)d_in[4];
    const float* Wq2 = (const float*)d_in[5];
    const float* Wk2 = (const float*)d_in[6];
    const float* Wv2 = (const float*)d_in[7];
    const float* Wo2 = (const float*)d_in[8];
    const float* W1  = (const float*)d_in[9];
    const float* W2  = (const float*)d_in[10];
    const float* g1  = (const float*)d_in[11];
    const float* g2  = (const float*)d_in[12];
    const float* g3  = (const float*)d_in[13];
    const int*   sep = (const int*)d_in[14];

    float* Xout = (float*)d_out;                    // final f32 X-layout output
    unsigned short* ws = (unsigned short*)d_ws;
    unsigned short* QKVb = ws;                      // [M][576] bf16 (aliases H1 [M][384])
    unsigned short* Tb   = QKVb + (size_t)M_ * 576;
    unsigned short* Ynb  = Tb + NBUF;               // rms-g1 output, XR layout
    unsigned short* Xcb  = Ynb + NBUF;              // rms-g2 output, X layout
    unsigned short* Xb   = Xcb + NBUF;              // inter-layer residual (layers 0-2)
    unsigned short* Wt   = Xb + NBUF;
    unsigned short* H1b  = QKVb;

    const dim3 blk(256);
    const dim3 blk512(512);
    const dim3 gQKV(M_ / 128, 3);                   // 256 x 3 (gemm v2)
    const dim3 gW1(M_ / 128, 2);                    // 256 x 2
    const dim3 g32(M_ / 32);                        // 1024 blocks (featblock)
    const dim3 g64(M_ / 64);                        // 512 blocks (rms64)
    const dim3 gA2(32 * H_ * 8);                    // (s,h) x 8 q-tiles of 128 rows

    k_convw_all<<<dim3(432 * L_), blk, 0, stream>>>(Wq1, Wk1, Wv1, Wo1, Wq2, Wk2, Wv2, Wo2, W1, W2, Wt);

    for (int i = 0; i < L_; ++i) {
        unsigned short* wl = Wt + (size_t)i * WPL;
        const unsigned short* wqkv1 = wl;
        const unsigned short* wo1   = wl + 3 * (size_t)E_ * E_;
        const unsigned short* wqkv2 = wl + 4 * (size_t)E_ * E_;
        const unsigned short* wo2   = wl + 7 * (size_t)E_ * E_;
        const unsigned short* w1    = wl + 8 * (size_t)E_ * E_;
        const unsigned short* w2    = wl + 8 * (size_t)E_ * E_ + (size_t)E_ * F_;
        const float* g1i = g1 + (size_t)i * E_;
        const float* g2i = g2 + (size_t)i * E_;
        const float* g3i = g3 + (size_t)i * E_;

        // --- fused feature-attention block: X/hidden -> Ynb (XR) ---
        if (i == 0)
            k_featblock<true><<<g32, blk, 0, stream>>>(hidden, wqkv1, wo1, g1i, Ynb);
        else
            k_featblock<false><<<g32, blk, 0, stream>>>(Xb, wqkv1, wo1, g1i, Ynb);
        // --- row attention block ---
        k_gemm_mfma<true, 0><<<gQKV, blk512, 0, stream>>>(Ynb, wqkv2, QKVb, 576, E_);
        k_attn2<<<gA2, blk512, 0, stream>>>(QKVb, Tb, sep);
        k_gemm_rms64<true, 3><<<g64, blk512, 0, stream>>>(Tb, wo2, Ynb, g2i, Xcb, E_);
        // --- MLP block ---
        k_gemm_mfma<true, 1><<<gW1, blk512, 0, stream>>>(Xcb, w1, H1b, F_, E_);
        if (i == L_ - 1)
            k_gemm_rms64<true, 4><<<g64, blk512, 0, stream>>>(H1b, w2, Xcb, g3i, Xout, F_);
        else
            k_gemm_rms64<true, 5><<<g64, blk512, 0, stream>>>(H1b, w2, Xcb, g3i, Xb, F_);
    }
}